// Round 6
// baseline (29110.693 us; speedup 1.0000x reference)
//
#include <hip/hip_runtime.h>
#include <hip/hip_bf16.h>
#include <math.h>

// ---------------------------------------------------------------------------
// Round 6: persistent cooperative kernel; round-3 phase structure, but ALL
// data moves via normal cached loads/stores. Cross-XCD coherence is provided
// by the barrier itself: ACQ_REL arrive (s_waitcnt + buffer_wbl2 -> L3),
// RELAXED poll (no inv storm), single ACQUIRE load after success
// (one buffer_inv -> refill from L3). Round 2 proved this chain correct for
// plain-stored data; round 3 proved the phase math. Round 3's 143us/step was
// agent-atomic data loads serviced at HBM (FETCH_SIZE 6.6MB/step) - removed.
// ---------------------------------------------------------------------------

#define NB    64
#define TENC  500
#define TDEC  200
#define EMBD  512
#define HID   1024
#define KSZ   128
#define VSZ   128
#define VOCAB 10000
#define K1    1664
#define K2    1152
#define NWG   64
#define NTH   512

typedef __bf16 bf16x8 __attribute__((ext_vector_type(8)));
typedef float f32x4 __attribute__((ext_vector_type(4)));
typedef unsigned long long u64;
#define MFMA16(a, b, c) __builtin_amdgcn_mfma_f32_16x16x32_bf16((a), (b), (c), 0, 0, 0)

// ws layout (bytes)
constexpr size_t OFF_BAR   = 0;          // cnt 8x64B @0, rel u32 @1024
constexpr size_t OFF_H1    = 4096;       // bf16 [2][64][1024] = 262144
constexpr size_t OFF_CTX   = 266240;     // bf16 [64][128] = 16384
constexpr size_t OFF_BS1   = 282624;     // f32 [4096]
constexpr size_t OFF_BS2   = 299008;     // f32 [512]
constexpr size_t OFF_W2T   = 301056;     // bf16 [144][512][8] = 1179648
constexpr size_t OFF_H2C   = 1480704;    // bf16 [12800][256] = 6553600
constexpr size_t OFF_W1    = 8034304;    // bf16 [4096][1664] = 13631488
constexpr size_t OFF_WOUT  = 21665792;   // bf16 [10000][256] = 5120000
constexpr size_t OFF_XEMB  = 26785792;   // bf16 [200][64][512] = 13107200
constexpr size_t BASE_END  = 39892992;
constexpr size_t OFF_KEYBF = 39892992;   // bf16 [64][500][128]
constexpr size_t OFF_VALBF = 48084992;   // bf16 [64][500][128]
constexpr size_t KV_END    = 56276992;

__device__ __forceinline__ float sigm(float x) { return 1.0f / (1.0f + __expf(-x)); }
__device__ __forceinline__ float ftanh(float x) {
  float ax = fabsf(x);
  float e = __expf(2.0f * ax);
  float tv = 1.0f - 2.0f / (e + 1.0f);
  return copysignf(tv, x);
}
__device__ __forceinline__ float bf2f(unsigned u) { return __uint_as_float(u << 16); }
__device__ __forceinline__ bf16x8 ldfrag(const __hip_bfloat16* p) {
  return *reinterpret_cast<const bf16x8*>(p);
}
__device__ __forceinline__ unsigned pack2bf(float a, float b) {
  __hip_bfloat16 ha = __float2bfloat16(a), hb = __float2bfloat16(b);
  unsigned short ua = *(unsigned short*)&ha, ub = *(unsigned short*)&hb;
  return (unsigned)ua | ((unsigned)ub << 16);
}

// ------------------------------------------------------------- prep kernels
__global__ __launch_bounds__(256) void k_prep_w1(const float* __restrict__ Wih1,
                                                 const float* __restrict__ Whh1,
                                                 const float* __restrict__ bih1,
                                                 const float* __restrict__ bhh1,
                                                 __hip_bfloat16* __restrict__ W1bf,
                                                 float* __restrict__ bsum1) {
  int r = blockIdx.x;
  const float* wi = Wih1 + (size_t)r * 640;
  const float* wh = Whh1 + (size_t)r * 1024;
  for (int k = threadIdx.x; k < K1; k += 256)
    W1bf[(size_t)r * K1 + k] = __float2bfloat16(k < 640 ? wi[k] : wh[k - 640]);
  if (threadIdx.x == 0) bsum1[r] = bih1[r] + bhh1[r];
}

__global__ __launch_bounds__(256) void k_prep_w2t(const float* __restrict__ Wih2,
                                                  const float* __restrict__ Whh2,
                                                  const float* __restrict__ bih2,
                                                  const float* __restrict__ bhh2,
                                                  __hip_bfloat16* __restrict__ W2T,
                                                  float* __restrict__ bsum2) {
  int r = blockIdx.x;  // 512 rows
  for (int idx = threadIdx.x; idx < K2; idx += 256) {
    int kb = idx >> 3, j = idx & 7;
    float v = (idx < 1024) ? Wih2[(size_t)r * 1024 + idx]
                           : Whh2[(size_t)r * 128 + idx - 1024];
    W2T[((size_t)(kb * 512 + r)) * 8 + j] = __float2bfloat16(v);
  }
  if (threadIdx.x == 0) bsum2[r] = bih2[r] + bhh2[r];
}

__global__ __launch_bounds__(256) void k_prep_wout(const float* __restrict__ Wout,
                                                   __hip_bfloat16* __restrict__ Woutbf) {
  int r0 = blockIdx.x * 16;
  for (int idx = threadIdx.x; idx < 16 * 256; idx += 256) {
    int r = r0 + (idx >> 8), k = idx & 255;
    Woutbf[(size_t)r * 256 + k] = __float2bfloat16(Wout[(size_t)r * 256 + k]);
  }
}

__global__ __launch_bounds__(256) void k_gather(const int* __restrict__ text,
                                                const float* __restrict__ emb,
                                                __hip_bfloat16* __restrict__ xembbf) {
  int t = blockIdx.x;
  __shared__ int tok[NB];
  if (threadIdx.x < NB) tok[threadIdx.x] = text[threadIdx.x * TDEC + t];
  __syncthreads();
  for (int idx = threadIdx.x; idx < NB * EMBD; idx += 256) {
    int n = idx >> 9, k = idx & 511;
    xembbf[((size_t)t * NB + n) * EMBD + k] =
        __float2bfloat16(emb[(size_t)tok[n] * EMBD + k]);
  }
}

__global__ __launch_bounds__(256) void k_prep_kv(const float* __restrict__ key,
                                                 const float* __restrict__ value,
                                                 __hip_bfloat16* __restrict__ keybf,
                                                 __hip_bfloat16* __restrict__ valbf) {
  int gsz = gridDim.x * 256;
  for (size_t i = blockIdx.x * 256 + threadIdx.x; i < (size_t)NB * TENC * KSZ; i += gsz) {
    keybf[i] = __float2bfloat16(key[i]);
    valbf[i] = __float2bfloat16(value[i]);
  }
}

// ---------------- grid barrier: ACQ_REL arrive, RELAXED poll, ACQUIRE once
__device__ __forceinline__ void gbar(unsigned* cnt, unsigned* rel, int ep, int wg) {
  asm volatile("s_waitcnt vmcnt(0)" ::: "memory");
  __syncthreads();
  int tid = threadIdx.x;
  if (tid == 0)
    __hip_atomic_fetch_add(&cnt[(wg & 7) << 4], 1u, __ATOMIC_ACQ_REL,
                           __HIP_MEMORY_SCOPE_AGENT);
  if (wg == 0 && tid < 64) {
    unsigned need = (unsigned)ep * 8u;
    for (;;) {
      unsigned v = __hip_atomic_load(&cnt[(tid & 7) << 4], __ATOMIC_RELAXED,
                                     __HIP_MEMORY_SCOPE_AGENT);
      if (__all((int)(v >= need))) break;
      __builtin_amdgcn_s_sleep(1);
    }
    // one acquire: synchronizes-with all 64 releasing RMWs (buffer_inv once)
    unsigned vv = __hip_atomic_load(&cnt[(tid & 7) << 4], __ATOMIC_ACQUIRE,
                                    __HIP_MEMORY_SCOPE_AGENT);
    (void)vv;
    if (tid == 0)
      __hip_atomic_store(rel, (unsigned)ep, __ATOMIC_RELEASE, __HIP_MEMORY_SCOPE_AGENT);
  }
  if (tid == 0) {
    while (__hip_atomic_load(rel, __ATOMIC_RELAXED, __HIP_MEMORY_SCOPE_AGENT) <
           (unsigned)ep)
      __builtin_amdgcn_s_sleep(1);
    unsigned rv = __hip_atomic_load(rel, __ATOMIC_ACQUIRE, __HIP_MEMORY_SCOPE_AGENT);
    (void)rv;
  }
  __syncthreads();
}

// ------------------------------------------------------- persistent kernel
struct LA {
  const float* key;
  const float* value;
  const int* slen;
  const __hip_bfloat16* keybf;
  const __hip_bfloat16* valbf;
  int kv;
  const __hip_bfloat16* W1bf;
  const __hip_bfloat16* W2T;
  const __hip_bfloat16* xembbf;
  const float* bsum1;
  const float* bsum2;
  __hip_bfloat16* h1bf;   // [2][64][1024]
  __hip_bfloat16* ctxbf;  // [64][128]
  __hip_bfloat16* h2cbf;  // [12800][256]
  unsigned* bar_cnt;
  unsigned* bar_rel;
};

__global__ __launch_bounds__(NTH) void k_loop(LA a) {
  const int wg = blockIdx.x, tid = threadIdx.x;
  const int lane = tid & 63, wid = tid >> 6;
  const int ln15 = lane & 15, lg = lane >> 4, ko = lg * 8;
  const int bg = wid & 3, kh = wid >> 2;
  const int d0 = wg * 16;

  __shared__ float bs1l[16][4];
  __shared__ float h2st[2][128];
  __shared__ float c2st[2][128];
  __shared__ float bs2l[4][128];
  __shared__ __align__(16) char smem[33792];
  float* part = (float*)smem;            // B: [4][4][64][4] f32 (16KB)
  float* gl   = (float*)(smem + 16384);  // B: [4][4][16][16] f32 (16KB)
  float* h1s  = (float*)smem;            // CA: [2][1024] f32 (8KB)
  float* g2   = (float*)(smem + 8192);   // CA: [2][512] f32 (4KB)
  float* e_l  = (float*)(smem + 12288);  // CA: [2][512] f32 (4KB)
  float* red  = (float*)(smem + 16384);  // CA: [2][256] f32 (2KB)
  float* ctxp = (float*)(smem + 18432);  // CA: [2][2][128] f32 (2KB)

  float creg0 = 0.f, creg1 = 0.f;  // persistent c1 (2 dims/thread)

  const __hip_bfloat16 *wb0, *wb1, *wb2, *wb3;
  {
    int g = ln15 & 3, s = ln15 >> 2;
    wb0 = a.W1bf + (size_t)(g * 1024 + d0 + 0 + s) * K1;
    wb1 = a.W1bf + (size_t)(g * 1024 + d0 + 4 + s) * K1;
    wb2 = a.W1bf + (size_t)(g * 1024 + d0 + 8 + s) * K1;
    wb3 = a.W1bf + (size_t)(g * 1024 + d0 + 12 + s) * K1;
  }
  const int nA = bg * 16 + ln15;  // A-operand batch row for this lane

  int len0 = 0, len1 = 0;
  if (wg < 32) { len0 = a.slen[wg * 2]; len1 = a.slen[wg * 2 + 1]; }

  // -------------------------------- prologue: biases to LDS, ctx0 = mean(V)
  if (tid < 64) bs1l[tid >> 2][tid & 3] = a.bsum1[(tid & 3) * 1024 + d0 + (tid >> 2)];
  if (wg < 32) {
    bs2l[tid >> 7][tid & 127] = a.bsum2[tid];
    if (tid < 256) { h2st[tid >> 7][tid & 127] = 0.f; c2st[tid >> 7][tid & 127] = 0.f; }
    __syncthreads();
    {
      int l = tid & 255, nl = tid >> 8;
      int n = wg * 2 + nl, len = nl ? len1 : len0;
      int v = l & 127, ph = l >> 7;
      float acc = 0.f;
      if (a.kv) {
        const unsigned short* vb = (const unsigned short*)a.valbf;
        for (int p = ph; p < len; p += 2)
          acc += bf2f(vb[((size_t)n * TENC + p) * VSZ + v]);
      } else {
        for (int p = ph; p < len; p += 2)
          acc += a.value[((size_t)n * TENC + p) * VSZ + v];
      }
      ctxp[(nl * 2 + ph) * 128 + v] = acc;
    }
    __syncthreads();
    if (tid < 128) {
      int nl = tid >> 6, vp = tid & 63, n = wg * 2 + nl;
      float invl = 1.f / (float)(nl ? len1 : len0);
      float c0 = (ctxp[(nl * 2) * 128 + 2 * vp] + ctxp[(nl * 2 + 1) * 128 + 2 * vp]) * invl;
      float c1 = (ctxp[(nl * 2) * 128 + 2 * vp + 1] + ctxp[(nl * 2 + 1) * 128 + 2 * vp + 1]) * invl;
      unsigned pk = pack2bf(c0, c1);
      *(unsigned*)(a.ctxbf + n * 128 + 2 * vp) = pk;
      *(unsigned*)&a.h2cbf[((size_t)0 * NB + n) * 256 + 128 + 2 * vp] = pk;
    }
  }
  int ep = 0;
  gbar(a.bar_cnt, a.bar_rel, ++ep, wg);

  // -------------------------------- main loop
  for (int t = 0; t < TDEC; ++t) {
    const int cur = t & 1;
    const __hip_bfloat16* h1c = a.h1bf + (size_t)cur * 65536;
    __hip_bfloat16* h1n = a.h1bf + (size_t)(cur ^ 1) * 65536;

    // ---------- phase B: LSTM1 (all 64 WGs; WG owns 16 h1 dims)
    {
      const __hip_bfloat16* ax = a.xembbf + ((size_t)t * NB + nA) * EMBD;
      const __hip_bfloat16* ac = a.ctxbf + nA * 128;
      const __hip_bfloat16* ah = h1c + nA * 1024;
      f32x4 q0 = {0, 0, 0, 0}, q1 = {0, 0, 0, 0}, q2 = {0, 0, 0, 0}, q3 = {0, 0, 0, 0};
      if (kh == 0) {
        #pragma unroll
        for (int s = 0; s < 16; ++s) {
          bf16x8 av = ldfrag(ax + s * 32 + ko);
          int o = s * 32 + ko;
          q0 = MFMA16(av, ldfrag(wb0 + o), q0);
          q1 = MFMA16(av, ldfrag(wb1 + o), q1);
          q2 = MFMA16(av, ldfrag(wb2 + o), q2);
          q3 = MFMA16(av, ldfrag(wb3 + o), q3);
        }
        #pragma unroll
        for (int s = 0; s < 4; ++s) {
          bf16x8 av = ldfrag(ac + s * 32 + ko);
          int o = 512 + s * 32 + ko;
          q0 = MFMA16(av, ldfrag(wb0 + o), q0);
          q1 = MFMA16(av, ldfrag(wb1 + o), q1);
          q2 = MFMA16(av, ldfrag(wb2 + o), q2);
          q3 = MFMA16(av, ldfrag(wb3 + o), q3);
        }
        #pragma unroll
        for (int s = 0; s < 6; ++s) {
          bf16x8 av = ldfrag(ah + s * 32 + ko);
          int o = 640 + s * 32 + ko;
          q0 = MFMA16(av, ldfrag(wb0 + o), q0);
          q1 = MFMA16(av, ldfrag(wb1 + o), q1);
          q2 = MFMA16(av, ldfrag(wb2 + o), q2);
          q3 = MFMA16(av, ldfrag(wb3 + o), q3);
        }
      } else {
        #pragma unroll
        for (int s = 0; s < 26; ++s) {
          bf16x8 av = ldfrag(ah + 192 + s * 32 + ko);
          int o = 832 + s * 32 + ko;
          q0 = MFMA16(av, ldfrag(wb0 + o), q0);
          q1 = MFMA16(av, ldfrag(wb1 + o), q1);
          q2 = MFMA16(av, ldfrag(wb2 + o), q2);
          q3 = MFMA16(av, ldfrag(wb3 + o), q3);
        }
      }
      if (kh == 1) {
        *(f32x4*)&part[(((bg * 4 + 0) * 64) + lane) * 4] = q0;
        *(f32x4*)&part[(((bg * 4 + 1) * 64) + lane) * 4] = q1;
        *(f32x4*)&part[(((bg * 4 + 2) * 64) + lane) * 4] = q2;
        *(f32x4*)&part[(((bg * 4 + 3) * 64) + lane) * 4] = q3;
      }
      __syncthreads();
      if (kh == 0) {
        q0 += *(f32x4*)&part[(((bg * 4 + 0) * 64) + lane) * 4];
        q1 += *(f32x4*)&part[(((bg * 4 + 1) * 64) + lane) * 4];
        q2 += *(f32x4*)&part[(((bg * 4 + 2) * 64) + lane) * 4];
        q3 += *(f32x4*)&part[(((bg * 4 + 3) * 64) + lane) * 4];
        #pragma unroll
        for (int r = 0; r < 4; ++r) {
          gl[((bg * 4 + 0) * 16 + (lg * 4 + r)) * 16 + ln15] = q0[r];
          gl[((bg * 4 + 1) * 16 + (lg * 4 + r)) * 16 + ln15] = q1[r];
          gl[((bg * 4 + 2) * 16 + (lg * 4 + r)) * 16 + ln15] = q2[r];
          gl[((bg * 4 + 3) * 16 + (lg * 4 + r)) * 16 + ln15] = q3[r];
        }
      }
      __syncthreads();
      {  // tail: thread owns (n, dim-pair)
        int n = tid >> 3, dp = tid & 7;
        int bgg = n >> 4, ii = n & 15;
        int t4 = dp >> 1, off = (dp & 1) * 8;
        float* gp = &gl[((bgg * 4 + t4) * 16 + ii) * 16 + off];
        float4 gA = *(float4*)gp;
        float4 gB = *(float4*)(gp + 4);
        int dA = dp * 2, dB = dp * 2 + 1;
        float I = sigm(gA.x + bs1l[dA][0]);
        float F = sigm(gA.y + bs1l[dA][1]);
        float G = ftanh(gA.z + bs1l[dA][2]);
        float O = sigm(gA.w + bs1l[dA][3]);
        float cv = F * creg0 + I * G;
        creg0 = cv;
        float hA = O * ftanh(cv);
        I = sigm(gB.x + bs1l[dB][0]);
        F = sigm(gB.y + bs1l[dB][1]);
        G = ftanh(gB.z + bs1l[dB][2]);
        O = sigm(gB.w + bs1l[dB][3]);
        cv = F * creg1 + I * G;
        creg1 = cv;
        float hB = O * ftanh(cv);
        *(unsigned*)(h1n + n * 1024 + d0 + dA) = pack2bf(hA, hB);
      }
    }
    gbar(a.bar_cnt, a.bar_rel, ++ep, wg);

    // ---------- phase CA: LSTM2 + attention (WGs 0..31, 2 batch rows each)
    if (wg < 32) {
      {  // stage h1 rows (2KB each) -> LDS fp32
        int row = tid >> 8, i4 = (tid & 255) << 2;
        u64 u = *(const u64*)(h1n + (wg * 2 + row) * 1024 + i4);
        h1s[row * 1024 + i4 + 0] = bf2f((unsigned)(u & 0xffffu));
        h1s[row * 1024 + i4 + 1] = bf2f((unsigned)((u >> 16) & 0xffffu));
        h1s[row * 1024 + i4 + 2] = bf2f((unsigned)((u >> 32) & 0xffffu));
        h1s[row * 1024 + i4 + 3] = bf2f((unsigned)(u >> 48));
      }
      __syncthreads();
      {  // lstm2: thread owns gate-row r for both n
        int r = tid;
        float a0 = 0.f, a1 = 0.f;
        #pragma unroll 8
        for (int kb = 0; kb < 144; ++kb) {
          uint4 wv = *(const uint4*)(a.W2T + (size_t)(kb * 512 + r) * 8);
          const float* iA = (kb < 128) ? &h1s[kb * 8] : &h2st[0][(kb - 128) * 8];
          const float* iB = (kb < 128) ? &h1s[1024 + kb * 8] : &h2st[1][(kb - 128) * 8];
          float w0 = bf2f(wv.x & 0xffffu), w1 = bf2f(wv.x >> 16);
          float w2 = bf2f(wv.y & 0xffffu), w3 = bf2f(wv.y >> 16);
          float w4 = bf2f(wv.z & 0xffffu), w5 = bf2f(wv.z >> 16);
          float w6 = bf2f(wv.w & 0xffffu), w7 = bf2f(wv.w >> 16);
          a0 += w0 * iA[0] + w1 * iA[1] + w2 * iA[2] + w3 * iA[3]
              + w4 * iA[4] + w5 * iA[5] + w6 * iA[6] + w7 * iA[7];
          a1 += w0 * iB[0] + w1 * iB[1] + w2 * iB[2] + w3 * iB[3]
              + w4 * iB[4] + w5 * iB[5] + w6 * iB[6] + w7 * iB[7];
        }
        g2[r] = a0;
        g2[512 + r] = a1;
      }
      __syncthreads();
      if (tid < 256) {  // combine gates, update c2/h2 (LDS state)
        int nl = tid >> 7, dd = tid & 127;
        float* gg = &g2[nl * 512];
        float I = sigm(gg[dd] + bs2l[0][dd]);
        float F = sigm(gg[128 + dd] + bs2l[1][dd]);
        float G = ftanh(gg[256 + dd] + bs2l[2][dd]);
        float O = sigm(gg[384 + dd] + bs2l[3][dd]);
        float cv = F * c2st[nl][dd] + I * G;
        c2st[nl][dd] = cv;
        float h = O * ftanh(cv);
        h2st[nl][dd] = h;
        a.h2cbf[((size_t)t * NB + wg * 2 + nl) * 256 + dd] = __float2bfloat16(h);
      }
      __syncthreads();
      if (t < TDEC - 1) {  // attention for step t+1 with fresh h2
        int l = tid & 255, nl = tid >> 8;
        int n = wg * 2 + nl, len = nl ? len1 : len0;
        int pA = l, pB = l + 256;
        auto edot = [&](int p) -> float {
          float s = 0.f;
          if (a.kv) {
            const uint4* kr = (const uint4*)(a.keybf + ((size_t)n * TENC + p) * KSZ);
            #pragma unroll
            for (int kk = 0; kk < 16; ++kk) {
              uint4 u = kr[kk];
              const float* hh = &h2st[nl][kk * 8];
              s += bf2f(u.x & 0xffffu) * hh[0] + bf2f(u.x >> 16) * hh[1]
                 + bf2f(u.y & 0xffffu) * hh[2] + bf2f(u.y >> 16) * hh[3]
                 + bf2f(u.z & 0xffffu) * hh[4] + bf2f(u.z >> 16) * hh[5]
                 + bf2f(u.w & 0xffffu) * hh[6] + bf2f(u.w >> 16) * hh[7];
            }
          } else {
            const float4* kr = (const float4*)(a.key + ((size_t)n * TENC + p) * KSZ);
            #pragma unroll 8
            for (int kk = 0; kk < 32; ++kk) {
              float4 u = kr[kk];
              const float* hh = &h2st[nl][kk * 4];
              s += u.x * hh[0] + u.y * hh[1] + u.z * hh[2] + u.w * hh[3];
            }
          }
          return s;
        };
        float eA = -1e9f, eB = -1e9f;
        if (pA < len) eA = edot(pA);
        if (pB < 500 && pB < len) eB = edot(pB);
        red[nl * 256 + l] = fmaxf(eA, eB);
        __syncthreads();
        for (int s2 = 128; s2 > 0; s2 >>= 1) {
          if (l < s2) {
            int b = nl * 256 + l;
            red[b] = fmaxf(red[b], red[b + s2]);
          }
          __syncthreads();
        }
        float m = red[nl * 256];
        __syncthreads();
        float xA = (pA < len) ? __expf(eA - m) : 0.f;
        float xB = (pB < len && pB < 500) ? __expf(eB - m) : 0.f;
        e_l[nl * 512 + pA] = xA;
        e_l[nl * 512 + pB] = xB;
        red[nl * 256 + l] = xA + xB;
        __syncthreads();
        for (int s2 = 128; s2 > 0; s2 >>= 1) {
          if (l < s2) {
            int b = nl * 256 + l;
            red[b] += red[b + s2];
          }
          __syncthreads();
        }
        float inv = 1.f / red[nl * 256];
        {
          int v = l & 127, ph = l >> 7;
          float accv = 0.f;
          if (a.kv) {
            const unsigned short* vb = (const unsigned short*)a.valbf;
            for (int p = ph; p < len; p += 2)
              accv += e_l[nl * 512 + p] * bf2f(vb[((size_t)n * TENC + p) * VSZ + v]);
          } else {
            for (int p = ph; p < len; p += 2)
              accv += e_l[nl * 512 + p] * a.value[((size_t)n * TENC + p) * VSZ + v];
          }
          ctxp[(nl * 2 + ph) * 128 + v] = accv * inv;
        }
        __syncthreads();
        if (tid < 128) {
          int nl2 = tid >> 6, vp = tid & 63, n2 = wg * 2 + nl2;
          float c0 = ctxp[(nl2 * 2) * 128 + 2 * vp] + ctxp[(nl2 * 2 + 1) * 128 + 2 * vp];
          float c1v = ctxp[(nl2 * 2) * 128 + 2 * vp + 1] + ctxp[(nl2 * 2 + 1) * 128 + 2 * vp + 1];
          unsigned pk = pack2bf(c0, c1v);
          *(unsigned*)(a.ctxbf + n2 * 128 + 2 * vp) = pk;
          *(unsigned*)&a.h2cbf[((size_t)(t + 1) * NB + n2) * 256 + 128 + 2 * vp] = pk;
        }
      }
    }
    gbar(a.bar_cnt, a.bar_rel, ++ep, wg);
  }
}

// ------------------------------------------------------ output projection
__global__ __launch_bounds__(256) void k_out(const __hip_bfloat16* __restrict__ h2cbf,
                                             const __hip_bfloat16* __restrict__ Woutbf,
                                             const float* __restrict__ bout,
                                             float* __restrict__ out) {
  int tid = threadIdx.x;
  int w = tid >> 6, lane = tid & 63;
  int ln15 = lane & 15, lg = lane >> 4, ko = lg * 8;
  int c0 = blockIdx.x * 64, m0 = blockIdx.y * 64;
  const __hip_bfloat16* ap = h2cbf + (size_t)(m0 + w * 16 + ln15) * 256;
  bf16x8 afr[8];
  #pragma unroll
  for (int kk = 0; kk < 8; ++kk) afr[kk] = ldfrag(ap + kk * 32 + ko);
  union U16 { uint4 u; bf16x8 v; };
  #pragma unroll
  for (int s = 0; s < 4; ++s) {
    int r = c0 + s * 16 + ln15;
    const __hip_bfloat16* bp = Woutbf + (size_t)r * 256;
    bool ok = r < VOCAB;
    f32x4 acc = {0.f, 0.f, 0.f, 0.f};
    #pragma unroll
    for (int kk = 0; kk < 8; ++kk) {
      U16 bv;
      bv.u = make_uint4(0, 0, 0, 0);
      if (ok) bv.v = ldfrag(bp + kk * 32 + ko);
      acc = MFMA16(afr[kk], bv.v, acc);
    }
    int c = c0 + s * 16 + ln15;
    if (c < VOCAB) {
      float bb = bout[c];
      #pragma unroll
      for (int reg = 0; reg < 4; ++reg) {
        int m = m0 + w * 16 + 4 * lg + reg;
        int n = m & 63, tt = m >> 6;
        out[((size_t)n * TDEC + tt) * VOCAB + c] = acc[reg] + bb;
      }
    }
  }
}

// ---------------------------------------------------------------------------
extern "C" void kernel_launch(void* const* d_in, const int* in_sizes, int n_in,
                              void* d_out, int out_size, void* d_ws, size_t ws_size,
                              hipStream_t stream) {
  (void)in_sizes; (void)n_in; (void)out_size;
  const float* key   = (const float*)d_in[0];
  const float* value = (const float*)d_in[1];
  const int*   slen  = (const int*)d_in[2];
  const int*   text  = (const int*)d_in[3];
  const float* emb   = (const float*)d_in[4];
  const float* Wih1  = (const float*)d_in[5];
  const float* Whh1  = (const float*)d_in[6];
  const float* bih1  = (const float*)d_in[7];
  const float* bhh1  = (const float*)d_in[8];
  const float* Wih2  = (const float*)d_in[9];
  const float* Whh2  = (const float*)d_in[10];
  const float* bih2  = (const float*)d_in[11];
  const float* bhh2  = (const float*)d_in[12];
  const float* Wout  = (const float*)d_in[13];
  const float* bout  = (const float*)d_in[14];
  float* out = (float*)d_out;
  char* ws = (char*)d_ws;

  __hip_bfloat16* W1bf   = (__hip_bfloat16*)(ws + OFF_W1);
  __hip_bfloat16* W2T    = (__hip_bfloat16*)(ws + OFF_W2T);
  __hip_bfloat16* Woutbf = (__hip_bfloat16*)(ws + OFF_WOUT);
  __hip_bfloat16* xembbf = (__hip_bfloat16*)(ws + OFF_XEMB);
  __hip_bfloat16* h2cbf  = (__hip_bfloat16*)(ws + OFF_H2C);
  float* bsum1 = (float*)(ws + OFF_BS1);
  float* bsum2 = (float*)(ws + OFF_BS2);
  int kv = (ws_size >= KV_END) ? 1 : 0;
  __hip_bfloat16* keybf = (__hip_bfloat16*)(ws + OFF_KEYBF);
  __hip_bfloat16* valbf = (__hip_bfloat16*)(ws + OFF_VALBF);

  hipMemsetAsync(d_ws, 0, 266240, stream);  // barrier flags + h1 buffers
  k_prep_w1<<<4096, 256, 0, stream>>>(Wih1, Whh1, bih1, bhh1, W1bf, bsum1);
  k_prep_w2t<<<512, 256, 0, stream>>>(Wih2, Whh2, bih2, bhh2, W2T, bsum2);
  k_prep_wout<<<625, 256, 0, stream>>>(Wout, Woutbf);
  k_gather<<<TDEC, 256, 0, stream>>>(text, emb, xembbf);
  if (kv) k_prep_kv<<<2048, 256, 0, stream>>>(key, value, keybf, valbf);

  LA la;
  la.key = key; la.value = value; la.slen = slen;
  la.keybf = keybf; la.valbf = valbf; la.kv = kv;
  la.W1bf = W1bf; la.W2T = W2T; la.xembbf = xembbf;
  la.bsum1 = bsum1; la.bsum2 = bsum2;
  la.h1bf = (__hip_bfloat16*)(ws + OFF_H1);
  la.ctxbf = (__hip_bfloat16*)(ws + OFF_CTX);
  la.h2cbf = h2cbf;
  la.bar_cnt = (unsigned*)(ws + OFF_BAR);
  la.bar_rel = (unsigned*)(ws + OFF_BAR + 1024);

  void* args[] = {&la};
  hipLaunchCooperativeKernel((void*)k_loop, dim3(NWG), dim3(NTH), args, 0, stream);

  k_out<<<dim3(157, 200), 256, 0, stream>>>(h2cbf, Woutbf, bout, out);
}

// Round 7
// 18057.269 us; speedup vs baseline: 1.6121x; 1.6121x over previous
//
#include <hip/hip_runtime.h>
#include <hip/hip_bf16.h>
#include <math.h>

// ---------------------------------------------------------------------------
// Round 7: persistent cooperative kernel with PER-STEP RING BUFFERS for the
// recurrent state (h1, ctx). Each buffer address is written exactly once
// (sc0/sc1 write-through stores -> L3) before any read, so no L2 can hold a
// stale copy and plain cached loads are safe with a pure-relaxed barrier.
// Weights/KV/xemb stay L2-warm across all 200 steps (no invalidation ever).
// Evidence: r3/r6 dur == FETCH_SIZE/48GB/s (forced-L2-miss latency bound);
// ring removes the forced misses. Fallback (ws too small): r6 mode
// (2 buffers + acquire-inv barrier), which passed at 29 ms.
// ---------------------------------------------------------------------------

#define NB    64
#define TENC  500
#define TDEC  200
#define EMBD  512
#define HID   1024
#define KSZ   128
#define VSZ   128
#define VOCAB 10000
#define K1    1664
#define K2    1152
#define NWG   64
#define NTH   512

typedef __bf16 bf16x8 __attribute__((ext_vector_type(8)));
typedef float f32x4 __attribute__((ext_vector_type(4)));
typedef unsigned long long u64;
#define MFMA16(a, b, c) __builtin_amdgcn_mfma_f32_16x16x32_bf16((a), (b), (c), 0, 0, 0)

// ws layout (bytes)
constexpr size_t OFF_BAR   = 0;          // cnt 8x64B + rel u32 @1024
constexpr size_t OFF_BS1   = 4096;       // f32 [4096]   -> 20480
constexpr size_t OFF_BS2   = 20480;      // f32 [512]    -> 22528
constexpr size_t OFF_W2T   = 22528;      // bf16 [144][512][8] -> 1202176
constexpr size_t OFF_H2C   = 1202176;    // bf16 [12800][256]  -> 7755776
constexpr size_t OFF_W1    = 7755776;    // bf16 [4096][1664]  -> 21387264
constexpr size_t OFF_WOUT  = 21387264;   // bf16 [10000][256]  -> 26507264
constexpr size_t OFF_XEMB  = 26507264;   // bf16 [200][64][512]-> 39614464
constexpr size_t OFF_H1R   = 39614464;   // bf16 [201][64][1024] -> 65959936
constexpr size_t OFF_CTXR  = 65959936;   // bf16 [201][64][128]  -> 69253120
constexpr size_t BIG_END   = 69253120;
constexpr size_t OFF_KEYBF = 69253120;   // bf16 [64][500][128] -> 77445120
constexpr size_t OFF_VALBF = 77445120;   // bf16 [64][500][128] -> 85637120
constexpr size_t KV_END    = 85637120;

__device__ __forceinline__ float sigm(float x) { return 1.0f / (1.0f + __expf(-x)); }
__device__ __forceinline__ float ftanh(float x) {
  float ax = fabsf(x);
  float e = __expf(2.0f * ax);
  float tv = 1.0f - 2.0f / (e + 1.0f);
  return copysignf(tv, x);
}
__device__ __forceinline__ float bf2f(unsigned u) { return __uint_as_float(u << 16); }
__device__ __forceinline__ bf16x8 ldfrag(const __hip_bfloat16* p) {
  return *reinterpret_cast<const bf16x8*>(p);
}
__device__ __forceinline__ void st_u32_sys(void* p, unsigned v) {
  __hip_atomic_store((unsigned*)p, v, __ATOMIC_RELAXED, __HIP_MEMORY_SCOPE_AGENT);
}
__device__ __forceinline__ unsigned pack2bf(float a, float b) {
  __hip_bfloat16 ha = __float2bfloat16(a), hb = __float2bfloat16(b);
  unsigned short ua = *(unsigned short*)&ha, ub = *(unsigned short*)&hb;
  return (unsigned)ua | ((unsigned)ub << 16);
}

// ------------------------------------------------------------- prep kernels
__global__ __launch_bounds__(256) void k_prep_w1(const float* __restrict__ Wih1,
                                                 const float* __restrict__ Whh1,
                                                 const float* __restrict__ bih1,
                                                 const float* __restrict__ bhh1,
                                                 __hip_bfloat16* __restrict__ W1bf,
                                                 float* __restrict__ bsum1) {
  int r = blockIdx.x;
  const float* wi = Wih1 + (size_t)r * 640;
  const float* wh = Whh1 + (size_t)r * 1024;
  for (int k = threadIdx.x; k < K1; k += 256)
    W1bf[(size_t)r * K1 + k] = __float2bfloat16(k < 640 ? wi[k] : wh[k - 640]);
  if (threadIdx.x == 0) bsum1[r] = bih1[r] + bhh1[r];
}

__global__ __launch_bounds__(256) void k_prep_w2t(const float* __restrict__ Wih2,
                                                  const float* __restrict__ Whh2,
                                                  const float* __restrict__ bih2,
                                                  const float* __restrict__ bhh2,
                                                  __hip_bfloat16* __restrict__ W2T,
                                                  float* __restrict__ bsum2) {
  int r = blockIdx.x;  // 512 rows
  for (int idx = threadIdx.x; idx < K2; idx += 256) {
    int kb = idx >> 3, j = idx & 7;
    float v = (idx < 1024) ? Wih2[(size_t)r * 1024 + idx]
                           : Whh2[(size_t)r * 128 + idx - 1024];
    W2T[((size_t)(kb * 512 + r)) * 8 + j] = __float2bfloat16(v);
  }
  if (threadIdx.x == 0) bsum2[r] = bih2[r] + bhh2[r];
}

__global__ __launch_bounds__(256) void k_prep_wout(const float* __restrict__ Wout,
                                                   __hip_bfloat16* __restrict__ Woutbf) {
  int r0 = blockIdx.x * 16;
  for (int idx = threadIdx.x; idx < 16 * 256; idx += 256) {
    int r = r0 + (idx >> 8), k = idx & 255;
    Woutbf[(size_t)r * 256 + k] = __float2bfloat16(Wout[(size_t)r * 256 + k]);
  }
}

__global__ __launch_bounds__(256) void k_gather(const int* __restrict__ text,
                                                const float* __restrict__ emb,
                                                __hip_bfloat16* __restrict__ xembbf) {
  int t = blockIdx.x;
  __shared__ int tok[NB];
  if (threadIdx.x < NB) tok[threadIdx.x] = text[threadIdx.x * TDEC + t];
  __syncthreads();
  for (int idx = threadIdx.x; idx < NB * EMBD; idx += 256) {
    int n = idx >> 9, k = idx & 511;
    xembbf[((size_t)t * NB + n) * EMBD + k] =
        __float2bfloat16(emb[(size_t)tok[n] * EMBD + k]);
  }
}

__global__ __launch_bounds__(256) void k_prep_kv(const float* __restrict__ key,
                                                 const float* __restrict__ value,
                                                 __hip_bfloat16* __restrict__ keybf,
                                                 __hip_bfloat16* __restrict__ valbf) {
  int gsz = gridDim.x * 256;
  for (size_t i = blockIdx.x * 256 + threadIdx.x; i < (size_t)NB * TENC * KSZ; i += gsz) {
    keybf[i] = __float2bfloat16(key[i]);
    valbf[i] = __float2bfloat16(value[i]);
  }
}

// ---------------- grid barrier: relaxed (big) or acquire-inv (small, r6)
__device__ __forceinline__ void gbar(unsigned* cnt, unsigned* rel, int ep, int wg,
                                     bool inv) {
  asm volatile("s_waitcnt vmcnt(0)" ::: "memory");
  __syncthreads();
  int tid = threadIdx.x;
  if (tid == 0) {
    if (inv)
      __hip_atomic_fetch_add(&cnt[(wg & 7) << 4], 1u, __ATOMIC_ACQ_REL,
                             __HIP_MEMORY_SCOPE_AGENT);
    else
      __hip_atomic_fetch_add(&cnt[(wg & 7) << 4], 1u, __ATOMIC_RELAXED,
                             __HIP_MEMORY_SCOPE_AGENT);
  }
  if (wg == 0 && tid < 64) {
    unsigned need = (unsigned)ep * 8u;
    for (;;) {
      unsigned v = __hip_atomic_load(&cnt[(tid & 7) << 4], __ATOMIC_RELAXED,
                                     __HIP_MEMORY_SCOPE_AGENT);
      if (__all((int)(v >= need))) break;
      __builtin_amdgcn_s_sleep(1);
    }
    if (inv) {
      unsigned vv = __hip_atomic_load(&cnt[(tid & 7) << 4], __ATOMIC_ACQUIRE,
                                      __HIP_MEMORY_SCOPE_AGENT);
      (void)vv;
    }
    if (tid == 0)
      __hip_atomic_store(rel, (unsigned)ep,
                         inv ? __ATOMIC_RELEASE : __ATOMIC_RELAXED,
                         __HIP_MEMORY_SCOPE_AGENT);
  }
  if (tid == 0) {
    while (__hip_atomic_load(rel, __ATOMIC_RELAXED, __HIP_MEMORY_SCOPE_AGENT) <
           (unsigned)ep)
      __builtin_amdgcn_s_sleep(1);
    if (inv) {
      unsigned rv = __hip_atomic_load(rel, __ATOMIC_ACQUIRE, __HIP_MEMORY_SCOPE_AGENT);
      (void)rv;
    }
  }
  __syncthreads();
}

// ------------------------------------------------------- persistent kernel
struct LA {
  const float* key;
  const float* value;
  const int* slen;
  const __hip_bfloat16* keybf;
  const __hip_bfloat16* valbf;
  int kv;
  int big;
  const __hip_bfloat16* W1bf;
  const __hip_bfloat16* W2T;
  const __hip_bfloat16* xembbf;
  const float* bsum1;
  const float* bsum2;
  __hip_bfloat16* h1r;    // ring [201][64][1024] (big) / [2][64][1024] (small)
  __hip_bfloat16* ctxr;   // ring [201][64][128]  (big) / [1][64][128]  (small)
  __hip_bfloat16* h2cbf;  // [12800][256]
  unsigned* bar_cnt;
  unsigned* bar_rel;
};

__global__ __launch_bounds__(NTH) void k_loop(LA a) {
  const int wg = blockIdx.x, tid = threadIdx.x;
  const int lane = tid & 63, wid = tid >> 6;
  const int ln15 = lane & 15, lg = lane >> 4, ko = lg * 8;
  const int bg = wid & 3, kh = wid >> 2;
  const int d0 = wg * 16;
  const bool inv = (a.big == 0);

  __shared__ float bs1l[16][4];
  __shared__ float h2st[128];
  __shared__ float c2st[128];
  __shared__ float bs2l[4][128];
  __shared__ __align__(16) char smem[33792];
  float* part = (float*)smem;            // B: [4][4][64][4] f32 (16KB)
  float* gl   = (float*)(smem + 16384);  // B: [4][4][16][16] f32 (16KB)
  float* h1s  = (float*)smem;            // CA: [1024] f32 (4KB)
  float* g2   = (float*)(smem + 4096);   // CA: [512] f32 (2KB)
  float* e_l  = (float*)(smem + 6144);   // CA: [512] f32 (2KB)
  float* red  = (float*)(smem + 8192);   // CA: [512] f32 (2KB)
  float* ctxp = (float*)(smem + 10240);  // CA: [8][128] f32 (4KB)

  float creg0 = 0.f, creg1 = 0.f;  // persistent c1 (2 dims/thread)

  const __hip_bfloat16 *wb0, *wb1, *wb2, *wb3;
  {
    int g = ln15 & 3, s = ln15 >> 2;
    wb0 = a.W1bf + (size_t)(g * 1024 + d0 + 0 + s) * K1;
    wb1 = a.W1bf + (size_t)(g * 1024 + d0 + 4 + s) * K1;
    wb2 = a.W1bf + (size_t)(g * 1024 + d0 + 8 + s) * K1;
    wb3 = a.W1bf + (size_t)(g * 1024 + d0 + 12 + s) * K1;
  }
  const int nA = bg * 16 + ln15;  // A-operand batch row for this lane
  const int n = wg;               // CA: one batch row per WG
  const int len = a.slen[n];

  // -------------------------------- prologue: biases, zero h2/c2, ctx0
  if (tid < 64) bs1l[tid >> 2][tid & 3] = a.bsum1[(tid & 3) * 1024 + d0 + (tid >> 2)];
  bs2l[tid >> 7][tid & 127] = a.bsum2[tid];
  if (tid < 128) { h2st[tid] = 0.f; c2st[tid] = 0.f; }
  __syncthreads();
  {  // ctx0 = mean(V rows)
    int v = tid & 127, ph = tid >> 7;  // ph 0..3
    float acc = 0.f;
    if (a.kv) {
      const unsigned short* vb = (const unsigned short*)a.valbf;
      for (int p = ph; p < len; p += 4)
        acc += bf2f(vb[((size_t)n * TENC + p) * VSZ + v]);
    } else {
      for (int p = ph; p < len; p += 4)
        acc += a.value[((size_t)n * TENC + p) * VSZ + v];
    }
    ctxp[ph * 128 + v] = acc;
  }
  __syncthreads();
  if (tid < 64) {
    int vp = tid;
    float invl = 1.f / (float)len;
    float c0 = (ctxp[0 * 128 + 2 * vp] + ctxp[1 * 128 + 2 * vp] +
                ctxp[2 * 128 + 2 * vp] + ctxp[3 * 128 + 2 * vp]) * invl;
    float c1 = (ctxp[0 * 128 + 2 * vp + 1] + ctxp[1 * 128 + 2 * vp + 1] +
                ctxp[2 * 128 + 2 * vp + 1] + ctxp[3 * 128 + 2 * vp + 1]) * invl;
    unsigned pk = pack2bf(c0, c1);
    st_u32_sys(a.ctxr + (size_t)n * 128 + 2 * vp, pk);  // ring idx 0
    *(unsigned*)&a.h2cbf[((size_t)0 * NB + n) * 256 + 128 + 2 * vp] = pk;
  }
  int ep = 0;
  gbar(a.bar_cnt, a.bar_rel, ++ep, wg, inv);

  // -------------------------------- main loop
  for (int t = 0; t < TDEC; ++t) {
    const __hip_bfloat16 *h1c, *ctxc;
    __hip_bfloat16 *h1n, *ctxn;
    if (a.big) {
      h1c = a.h1r + (size_t)t * 65536;        // h1(t-1): ring idx t
      h1n = a.h1r + (size_t)(t + 1) * 65536;  // h1(t):   ring idx t+1
      ctxc = a.ctxr + (size_t)t * 8192;       // ctx(t):  ring idx t
      ctxn = a.ctxr + (size_t)(t + 1) * 8192;
    } else {
      h1c = a.h1r + (size_t)(t & 1) * 65536;
      h1n = a.h1r + (size_t)((t + 1) & 1) * 65536;
      ctxc = a.ctxr;
      ctxn = a.ctxr;
    }

    // ---------- phase B: LSTM1 (all 64 WGs; WG owns 16 h1 dims)
    {
      const __hip_bfloat16* ax = a.xembbf + ((size_t)t * NB + nA) * EMBD;
      const __hip_bfloat16* ac = ctxc + nA * 128;
      const __hip_bfloat16* ah = h1c + nA * 1024;
      f32x4 q0 = {0, 0, 0, 0}, q1 = {0, 0, 0, 0}, q2 = {0, 0, 0, 0}, q3 = {0, 0, 0, 0};
      if (kh == 0) {
        #pragma unroll
        for (int s = 0; s < 16; ++s) {
          bf16x8 av = ldfrag(ax + s * 32 + ko);
          int o = s * 32 + ko;
          q0 = MFMA16(av, ldfrag(wb0 + o), q0);
          q1 = MFMA16(av, ldfrag(wb1 + o), q1);
          q2 = MFMA16(av, ldfrag(wb2 + o), q2);
          q3 = MFMA16(av, ldfrag(wb3 + o), q3);
        }
        #pragma unroll
        for (int s = 0; s < 4; ++s) {
          bf16x8 av = ldfrag(ac + s * 32 + ko);
          int o = 512 + s * 32 + ko;
          q0 = MFMA16(av, ldfrag(wb0 + o), q0);
          q1 = MFMA16(av, ldfrag(wb1 + o), q1);
          q2 = MFMA16(av, ldfrag(wb2 + o), q2);
          q3 = MFMA16(av, ldfrag(wb3 + o), q3);
        }
        #pragma unroll
        for (int s = 0; s < 6; ++s) {
          bf16x8 av = ldfrag(ah + s * 32 + ko);
          int o = 640 + s * 32 + ko;
          q0 = MFMA16(av, ldfrag(wb0 + o), q0);
          q1 = MFMA16(av, ldfrag(wb1 + o), q1);
          q2 = MFMA16(av, ldfrag(wb2 + o), q2);
          q3 = MFMA16(av, ldfrag(wb3 + o), q3);
        }
      } else {
        #pragma unroll
        for (int s = 0; s < 26; ++s) {
          bf16x8 av = ldfrag(ah + 192 + s * 32 + ko);
          int o = 832 + s * 32 + ko;
          q0 = MFMA16(av, ldfrag(wb0 + o), q0);
          q1 = MFMA16(av, ldfrag(wb1 + o), q1);
          q2 = MFMA16(av, ldfrag(wb2 + o), q2);
          q3 = MFMA16(av, ldfrag(wb3 + o), q3);
        }
      }
      if (kh == 1) {
        *(f32x4*)&part[(((bg * 4 + 0) * 64) + lane) * 4] = q0;
        *(f32x4*)&part[(((bg * 4 + 1) * 64) + lane) * 4] = q1;
        *(f32x4*)&part[(((bg * 4 + 2) * 64) + lane) * 4] = q2;
        *(f32x4*)&part[(((bg * 4 + 3) * 64) + lane) * 4] = q3;
      }
      __syncthreads();
      if (kh == 0) {
        q0 += *(f32x4*)&part[(((bg * 4 + 0) * 64) + lane) * 4];
        q1 += *(f32x4*)&part[(((bg * 4 + 1) * 64) + lane) * 4];
        q2 += *(f32x4*)&part[(((bg * 4 + 2) * 64) + lane) * 4];
        q3 += *(f32x4*)&part[(((bg * 4 + 3) * 64) + lane) * 4];
        #pragma unroll
        for (int r = 0; r < 4; ++r) {
          gl[((bg * 4 + 0) * 16 + (lg * 4 + r)) * 16 + ln15] = q0[r];
          gl[((bg * 4 + 1) * 16 + (lg * 4 + r)) * 16 + ln15] = q1[r];
          gl[((bg * 4 + 2) * 16 + (lg * 4 + r)) * 16 + ln15] = q2[r];
          gl[((bg * 4 + 3) * 16 + (lg * 4 + r)) * 16 + ln15] = q3[r];
        }
      }
      __syncthreads();
      {  // tail: thread owns (n, dim-pair)
        int nn = tid >> 3, dp = tid & 7;
        int bgg = nn >> 4, ii = nn & 15;
        int t4 = dp >> 1, off = (dp & 1) * 8;
        float* gp = &gl[((bgg * 4 + t4) * 16 + ii) * 16 + off];
        float4 gA = *(float4*)gp;
        float4 gB = *(float4*)(gp + 4);
        int dA = dp * 2, dB = dp * 2 + 1;
        float I = sigm(gA.x + bs1l[dA][0]);
        float F = sigm(gA.y + bs1l[dA][1]);
        float G = ftanh(gA.z + bs1l[dA][2]);
        float O = sigm(gA.w + bs1l[dA][3]);
        float cv = F * creg0 + I * G;
        creg0 = cv;
        float hA = O * ftanh(cv);
        I = sigm(gB.x + bs1l[dB][0]);
        F = sigm(gB.y + bs1l[dB][1]);
        G = ftanh(gB.z + bs1l[dB][2]);
        O = sigm(gB.w + bs1l[dB][3]);
        cv = F * creg1 + I * G;
        creg1 = cv;
        float hB = O * ftanh(cv);
        st_u32_sys(h1n + nn * 1024 + d0 + dA, pack2bf(hA, hB));
      }
    }
    gbar(a.bar_cnt, a.bar_rel, ++ep, wg, inv);

    // ---------- phase CA: LSTM2 + attention (all 64 WGs, one batch row each)
    {
      if (tid < 256) {  // stage h1 row n -> LDS fp32 (2KB)
        u64 u = *(const u64*)(h1n + (size_t)n * 1024 + tid * 4);
        h1s[tid * 4 + 0] = bf2f((unsigned)(u & 0xffffu));
        h1s[tid * 4 + 1] = bf2f((unsigned)((u >> 16) & 0xffffu));
        h1s[tid * 4 + 2] = bf2f((unsigned)((u >> 32) & 0xffffu));
        h1s[tid * 4 + 3] = bf2f((unsigned)(u >> 48));
      }
      __syncthreads();
      {  // lstm2: thread owns gate row tid
        int r = tid;
        float accg = 0.f;
        #pragma unroll 8
        for (int kb = 0; kb < 144; ++kb) {
          uint4 wv = *(const uint4*)(a.W2T + ((size_t)kb * 512 + r) * 8);
          const float* in = (kb < 128) ? &h1s[kb * 8] : &h2st[(kb - 128) * 8];
          accg += bf2f(wv.x & 0xffffu) * in[0] + bf2f(wv.x >> 16) * in[1]
                + bf2f(wv.y & 0xffffu) * in[2] + bf2f(wv.y >> 16) * in[3]
                + bf2f(wv.z & 0xffffu) * in[4] + bf2f(wv.z >> 16) * in[5]
                + bf2f(wv.w & 0xffffu) * in[6] + bf2f(wv.w >> 16) * in[7];
        }
        g2[r] = accg;
      }
      __syncthreads();
      if (tid < 128) {
        int dd = tid;
        float I = sigm(g2[dd] + bs2l[0][dd]);
        float F = sigm(g2[128 + dd] + bs2l[1][dd]);
        float G = ftanh(g2[256 + dd] + bs2l[2][dd]);
        float O = sigm(g2[384 + dd] + bs2l[3][dd]);
        float cv = F * c2st[dd] + I * G;
        c2st[dd] = cv;
        float h = O * ftanh(cv);
        h2st[dd] = h;
        a.h2cbf[((size_t)t * NB + n) * 256 + dd] = __float2bfloat16(h);
      }
      __syncthreads();
      if (t < TDEC - 1) {  // attention for step t+1 with fresh h2
        float e = -INFINITY;
        if (tid < len) {
          float s = 0.f;
          if (a.kv) {
            const uint4* kr = (const uint4*)(a.keybf + ((size_t)n * TENC + tid) * KSZ);
            #pragma unroll
            for (int kk = 0; kk < 16; ++kk) {
              uint4 u = kr[kk];
              const float* hh = &h2st[kk * 8];
              s += bf2f(u.x & 0xffffu) * hh[0] + bf2f(u.x >> 16) * hh[1]
                 + bf2f(u.y & 0xffffu) * hh[2] + bf2f(u.y >> 16) * hh[3]
                 + bf2f(u.z & 0xffffu) * hh[4] + bf2f(u.z >> 16) * hh[5]
                 + bf2f(u.w & 0xffffu) * hh[6] + bf2f(u.w >> 16) * hh[7];
            }
          } else {
            const float4* kr = (const float4*)(a.key + ((size_t)n * TENC + tid) * KSZ);
            #pragma unroll 8
            for (int kk = 0; kk < 32; ++kk) {
              float4 u = kr[kk];
              const float* hh = &h2st[kk * 4];
              s += u.x * hh[0] + u.y * hh[1] + u.z * hh[2] + u.w * hh[3];
            }
          }
          e = s;
        }
        red[tid] = e;
        __syncthreads();
        for (int s2 = 256; s2 > 0; s2 >>= 1) {
          if (tid < s2) red[tid] = fmaxf(red[tid], red[tid + s2]);
          __syncthreads();
        }
        float m = red[0];
        __syncthreads();
        float ex = (tid < len) ? __expf(e - m) : 0.f;
        e_l[tid] = ex;
        red[tid] = ex;
        __syncthreads();
        for (int s2 = 256; s2 > 0; s2 >>= 1) {
          if (tid < s2) red[tid] += red[tid + s2];
          __syncthreads();
        }
        float invs = 1.f / red[0];
        {  // PV: wave w handles p = w, w+8, ...; lanes cover 128 v-dims
          int w = tid >> 6, ln = tid & 63;
          float a0 = 0.f, a1 = 0.f;
          if (a.kv) {
            const unsigned short* vb = (const unsigned short*)a.valbf;
            for (int p = w; p < len; p += 8) {
              unsigned u = *(const unsigned*)(vb + ((size_t)n * TENC + p) * VSZ + 2 * ln);
              float ew = e_l[p];
              a0 += ew * bf2f(u & 0xffffu);
              a1 += ew * bf2f(u >> 16);
            }
          } else {
            for (int p = w; p < len; p += 8) {
              float2 vv = *(const float2*)(a.value + ((size_t)n * TENC + p) * VSZ + 2 * ln);
              float ew = e_l[p];
              a0 += ew * vv.x;
              a1 += ew * vv.y;
            }
          }
          ctxp[w * 128 + 2 * ln] = a0;
          ctxp[w * 128 + 2 * ln + 1] = a1;
        }
        __syncthreads();
        if (tid < 64) {
          int vp = tid;
          float c0 = 0.f, c1 = 0.f;
          #pragma unroll
          for (int w2 = 0; w2 < 8; ++w2) {
            c0 += ctxp[w2 * 128 + 2 * vp];
            c1 += ctxp[w2 * 128 + 2 * vp + 1];
          }
          unsigned pk = pack2bf(c0 * invs, c1 * invs);
          st_u32_sys(ctxn + (size_t)n * 128 + 2 * vp, pk);
          *(unsigned*)&a.h2cbf[((size_t)(t + 1) * NB + n) * 256 + 128 + 2 * vp] = pk;
        }
      }
    }
    gbar(a.bar_cnt, a.bar_rel, ++ep, wg, inv);
  }
}

// ------------------------------------------------------ output projection
__global__ __launch_bounds__(256) void k_out(const __hip_bfloat16* __restrict__ h2cbf,
                                             const __hip_bfloat16* __restrict__ Woutbf,
                                             const float* __restrict__ bout,
                                             float* __restrict__ out) {
  int tid = threadIdx.x;
  int w = tid >> 6, lane = tid & 63;
  int ln15 = lane & 15, lg = lane >> 4, ko = lg * 8;
  int c0 = blockIdx.x * 64, m0 = blockIdx.y * 64;
  const __hip_bfloat16* ap = h2cbf + (size_t)(m0 + w * 16 + ln15) * 256;
  bf16x8 afr[8];
  #pragma unroll
  for (int kk = 0; kk < 8; ++kk) afr[kk] = ldfrag(ap + kk * 32 + ko);
  union U16 { uint4 u; bf16x8 v; };
  #pragma unroll
  for (int s = 0; s < 4; ++s) {
    int r = c0 + s * 16 + ln15;
    const __hip_bfloat16* bp = Woutbf + (size_t)r * 256;
    bool ok = r < VOCAB;
    f32x4 acc = {0.f, 0.f, 0.f, 0.f};
    #pragma unroll
    for (int kk = 0; kk < 8; ++kk) {
      U16 bv;
      bv.u = make_uint4(0, 0, 0, 0);
      if (ok) bv.v = ldfrag(bp + kk * 32 + ko);
      acc = MFMA16(afr[kk], bv.v, acc);
    }
    int c = c0 + s * 16 + ln15;
    if (c < VOCAB) {
      float bb = bout[c];
      #pragma unroll
      for (int reg = 0; reg < 4; ++reg) {
        int m = m0 + w * 16 + 4 * lg + reg;
        int n = m & 63, tt = m >> 6;
        out[((size_t)n * TDEC + tt) * VOCAB + c] = acc[reg] + bb;
      }
    }
  }
}

// ---------------------------------------------------------------------------
extern "C" void kernel_launch(void* const* d_in, const int* in_sizes, int n_in,
                              void* d_out, int out_size, void* d_ws, size_t ws_size,
                              hipStream_t stream) {
  (void)in_sizes; (void)n_in; (void)out_size;
  const float* key   = (const float*)d_in[0];
  const float* value = (const float*)d_in[1];
  const int*   slen  = (const int*)d_in[2];
  const int*   text  = (const int*)d_in[3];
  const float* emb   = (const float*)d_in[4];
  const float* Wih1  = (const float*)d_in[5];
  const float* Whh1  = (const float*)d_in[6];
  const float* bih1  = (const float*)d_in[7];
  const float* bhh1  = (const float*)d_in[8];
  const float* Wih2  = (const float*)d_in[9];
  const float* Whh2  = (const float*)d_in[10];
  const float* bih2  = (const float*)d_in[11];
  const float* bhh2  = (const float*)d_in[12];
  const float* Wout  = (const float*)d_in[13];
  const float* bout  = (const float*)d_in[14];
  float* out = (float*)d_out;
  char* ws = (char*)d_ws;

  int big = (ws_size >= BIG_END) ? 1 : 0;
  int kv  = (ws_size >= KV_END) ? 1 : 0;

  __hip_bfloat16* W1bf   = (__hip_bfloat16*)(ws + OFF_W1);
  __hip_bfloat16* W2T    = (__hip_bfloat16*)(ws + OFF_W2T);
  __hip_bfloat16* Woutbf = (__hip_bfloat16*)(ws + OFF_WOUT);
  __hip_bfloat16* xembbf = (__hip_bfloat16*)(ws + OFF_XEMB);
  __hip_bfloat16* h2cbf  = (__hip_bfloat16*)(ws + OFF_H2C);
  float* bsum1 = (float*)(ws + OFF_BS1);
  float* bsum2 = (float*)(ws + OFF_BS2);
  __hip_bfloat16* keybf = (__hip_bfloat16*)(ws + OFF_KEYBF);
  __hip_bfloat16* valbf = (__hip_bfloat16*)(ws + OFF_VALBF);

  // zero barrier flags + h1 ring buffers 0 and 1 (covers both modes)
  hipMemsetAsync(ws, 0, 4096, stream);
  hipMemsetAsync(ws + OFF_H1R, 0, 262144, stream);
  k_prep_w1<<<4096, 256, 0, stream>>>(Wih1, Whh1, bih1, bhh1, W1bf, bsum1);
  k_prep_w2t<<<512, 256, 0, stream>>>(Wih2, Whh2, bih2, bhh2, W2T, bsum2);
  k_prep_wout<<<625, 256, 0, stream>>>(Wout, Woutbf);
  k_gather<<<TDEC, 256, 0, stream>>>(text, emb, xembbf);
  if (kv) k_prep_kv<<<2048, 256, 0, stream>>>(key, value, keybf, valbf);

  LA la;
  la.key = key; la.value = value; la.slen = slen;
  la.keybf = keybf; la.valbf = valbf; la.kv = kv; la.big = big;
  la.W1bf = W1bf; la.W2T = W2T; la.xembbf = xembbf;
  la.bsum1 = bsum1; la.bsum2 = bsum2;
  la.h1r = (__hip_bfloat16*)(ws + OFF_H1R);
  la.ctxr = (__hip_bfloat16*)(ws + OFF_CTXR);
  la.h2cbf = h2cbf;
  la.bar_cnt = (unsigned*)(ws + OFF_BAR);
  la.bar_rel = (unsigned*)(ws + OFF_BAR + 1024);

  void* args[] = {&la};
  hipLaunchCooperativeKernel((void*)k_loop, dim3(NWG), dim3(NTH), args, 0, stream);

  k_out<<<dim3(157, 200), 256, 0, stream>>>(h2cbf, Woutbf, bout, out);
}

// Round 9
// 13739.586 us; speedup vs baseline: 2.1187x; 1.3143x over previous
//
#include <hip/hip_runtime.h>
#include <hip/hip_bf16.h>
#include <math.h>

// ---------------------------------------------------------------------------
// Round 9: identical structure to round 8 (dim-parallel LSTM2 MFMA phase +
// output projection fused into the persistent kernel, pipelined per step by
// polling the barrier release epoch). Only change: the illegal
// __builtin_nontemporal_load(uint4*) is replaced by two u64 nontemporal
// loads (scalar ints are accepted by the builtin).
// ---------------------------------------------------------------------------

#define NB    64
#define TENC  500
#define TDEC  200
#define EMBD  512
#define HID   1024
#define KSZ   128
#define VSZ   128
#define VOCAB 10000
#define K1    1664
#define K2    1152
#define NWG   256
#define NTH   512

typedef __bf16 bf16x8 __attribute__((ext_vector_type(8)));
typedef float f32x4 __attribute__((ext_vector_type(4)));
typedef unsigned long long u64;
#define MFMA16(a, b, c) __builtin_amdgcn_mfma_f32_16x16x32_bf16((a), (b), (c), 0, 0, 0)

// ws layout (bytes)
constexpr size_t OFF_BAR   = 0;          // cnt 8x64B + rel u32 @1024
constexpr size_t OFF_BS1   = 4096;       // f32 [4096]
constexpr size_t OFF_BS2   = 20480;      // f32 [512]
constexpr size_t OFF_W2    = 22528;      // bf16 [512][1152] = 1179648
constexpr size_t OFF_H2C   = 1202176;    // bf16 [12800][256] = 6553600
constexpr size_t OFF_W1    = 7755776;    // bf16 [4096][1664] = 13631488
constexpr size_t OFF_WOUT  = 21387264;   // bf16 [10000][256] = 5120000
constexpr size_t OFF_XEMB  = 26507264;   // bf16 [200][64][512] = 13107200
constexpr size_t OFF_H1R   = 39614464;   // bf16 [201][64][1024] = 26345472
constexpr size_t OFF_CTXR  = 65959936;   // bf16 [201][64][128] = 3293184
constexpr size_t BIG_END   = 69253120;
constexpr size_t OFF_KEYBF = 69253120;   // bf16 [64][500][128]
constexpr size_t OFF_VALBF = 77445120;   // bf16 [64][500][128]
constexpr size_t KV_END    = 85637120;

__device__ __forceinline__ float sigm(float x) { return 1.0f / (1.0f + __expf(-x)); }
__device__ __forceinline__ float ftanh(float x) {
  float ax = fabsf(x);
  float e = __expf(2.0f * ax);
  float tv = 1.0f - 2.0f / (e + 1.0f);
  return copysignf(tv, x);
}
__device__ __forceinline__ float bf2f(unsigned u) { return __uint_as_float(u << 16); }
__device__ __forceinline__ bf16x8 ldfrag(const __hip_bfloat16* p) {
  return *reinterpret_cast<const bf16x8*>(p);
}
__device__ __forceinline__ bf16x8 ldfrag_nt(const __hip_bfloat16* p) {
  union { u64 u[2]; bf16x8 v; } r;
  r.u[0] = __builtin_nontemporal_load((const u64*)p);
  r.u[1] = __builtin_nontemporal_load((const u64*)(p + 4));
  return r.v;
}
__device__ __forceinline__ void st_u32_sys(void* p, unsigned v) {
  __hip_atomic_store((unsigned*)p, v, __ATOMIC_RELAXED, __HIP_MEMORY_SCOPE_AGENT);
}
__device__ __forceinline__ unsigned pack2bf(float a, float b) {
  __hip_bfloat16 ha = __float2bfloat16(a), hb = __float2bfloat16(b);
  unsigned short ua = *(unsigned short*)&ha, ub = *(unsigned short*)&hb;
  return (unsigned)ua | ((unsigned)ub << 16);
}

// ------------------------------------------------------------- prep kernels
__global__ __launch_bounds__(256) void k_prep_w1(const float* __restrict__ Wih1,
                                                 const float* __restrict__ Whh1,
                                                 const float* __restrict__ bih1,
                                                 const float* __restrict__ bhh1,
                                                 __hip_bfloat16* __restrict__ W1bf,
                                                 float* __restrict__ bsum1) {
  int r = blockIdx.x;
  const float* wi = Wih1 + (size_t)r * 640;
  const float* wh = Whh1 + (size_t)r * 1024;
  for (int k = threadIdx.x; k < K1; k += 256)
    W1bf[(size_t)r * K1 + k] = __float2bfloat16(k < 640 ? wi[k] : wh[k - 640]);
  if (threadIdx.x == 0) bsum1[r] = bih1[r] + bhh1[r];
}

__global__ __launch_bounds__(256) void k_prep_w2(const float* __restrict__ Wih2,
                                                 const float* __restrict__ Whh2,
                                                 const float* __restrict__ bih2,
                                                 const float* __restrict__ bhh2,
                                                 __hip_bfloat16* __restrict__ W2bf,
                                                 float* __restrict__ bsum2) {
  int r = blockIdx.x;  // 512 rows
  for (int k = threadIdx.x; k < K2; k += 256)
    W2bf[(size_t)r * K2 + k] =
        __float2bfloat16(k < 1024 ? Wih2[(size_t)r * 1024 + k]
                                  : Whh2[(size_t)r * 128 + k - 1024]);
  if (threadIdx.x == 0) bsum2[r] = bih2[r] + bhh2[r];
}

__global__ __launch_bounds__(256) void k_prep_wout(const float* __restrict__ Wout,
                                                   __hip_bfloat16* __restrict__ Woutbf) {
  int r0 = blockIdx.x * 16;
  for (int idx = threadIdx.x; idx < 16 * 256; idx += 256) {
    int r = r0 + (idx >> 8), k = idx & 255;
    Woutbf[(size_t)r * 256 + k] = __float2bfloat16(Wout[(size_t)r * 256 + k]);
  }
}

__global__ __launch_bounds__(256) void k_gather(const int* __restrict__ text,
                                                const float* __restrict__ emb,
                                                __hip_bfloat16* __restrict__ xembbf) {
  int t = blockIdx.x;
  __shared__ int tok[NB];
  if (threadIdx.x < NB) tok[threadIdx.x] = text[threadIdx.x * TDEC + t];
  __syncthreads();
  for (int idx = threadIdx.x; idx < NB * EMBD; idx += 256) {
    int n = idx >> 9, k = idx & 511;
    xembbf[((size_t)t * NB + n) * EMBD + k] =
        __float2bfloat16(emb[(size_t)tok[n] * EMBD + k]);
  }
}

__global__ __launch_bounds__(256) void k_prep_kv(const float* __restrict__ key,
                                                 const float* __restrict__ value,
                                                 __hip_bfloat16* __restrict__ keybf,
                                                 __hip_bfloat16* __restrict__ valbf) {
  int gsz = gridDim.x * 256;
  for (size_t i = blockIdx.x * 256 + threadIdx.x; i < (size_t)NB * TENC * KSZ; i += gsz) {
    keybf[i] = __float2bfloat16(key[i]);
    valbf[i] = __float2bfloat16(value[i]);
  }
}

// ---------------- grid barrier: relaxed (big) or acquire-inv (small)
__device__ __forceinline__ void gbar(unsigned* cnt, unsigned* rel, int ep, int wg,
                                     bool inv) {
  asm volatile("s_waitcnt vmcnt(0)" ::: "memory");
  __syncthreads();
  int tid = threadIdx.x;
  if (tid == 0) {
    if (inv)
      __hip_atomic_fetch_add(&cnt[(wg & 7) << 4], 1u, __ATOMIC_ACQ_REL,
                             __HIP_MEMORY_SCOPE_AGENT);
    else
      __hip_atomic_fetch_add(&cnt[(wg & 7) << 4], 1u, __ATOMIC_RELAXED,
                             __HIP_MEMORY_SCOPE_AGENT);
  }
  if (wg == 0 && tid < 64) {
    unsigned need = (unsigned)ep * 8u;
    for (;;) {
      unsigned v = __hip_atomic_load(&cnt[(tid & 7) << 4], __ATOMIC_RELAXED,
                                     __HIP_MEMORY_SCOPE_AGENT);
      if (__all((int)(v >= need))) break;
      __builtin_amdgcn_s_sleep(1);
    }
    if (inv) {
      unsigned vv = __hip_atomic_load(&cnt[(tid & 7) << 4], __ATOMIC_ACQUIRE,
                                      __HIP_MEMORY_SCOPE_AGENT);
      (void)vv;
    }
    if (tid == 0)
      __hip_atomic_store(rel, (unsigned)ep,
                         inv ? __ATOMIC_RELEASE : __ATOMIC_RELAXED,
                         __HIP_MEMORY_SCOPE_AGENT);
  }
  if (tid == 0) {
    while (__hip_atomic_load(rel, __ATOMIC_RELAXED, __HIP_MEMORY_SCOPE_AGENT) <
           (unsigned)ep)
      __builtin_amdgcn_s_sleep(1);
    if (inv) {
      unsigned rv = __hip_atomic_load(rel, __ATOMIC_ACQUIRE, __HIP_MEMORY_SCOPE_AGENT);
      (void)rv;
    }
  }
  __syncthreads();
}

// ------------------------------------------------------- persistent kernel
struct LA {
  const float* key;
  const float* value;
  const int* slen;
  const __hip_bfloat16* keybf;
  const __hip_bfloat16* valbf;
  int kv;
  int big;
  const __hip_bfloat16* W1bf;
  const __hip_bfloat16* W2bf;
  const __hip_bfloat16* Woutbf;
  const __hip_bfloat16* xembbf;
  const float* bsum1;
  const float* bsum2;
  const float* bout;
  float* out;
  __hip_bfloat16* h1r;    // ring [201][64][1024] (big) / [2][64][1024] (small)
  __hip_bfloat16* ctxr;   // ring [201][64][128]  (big) / [1][64][128]  (small)
  __hip_bfloat16* h2cbf;  // [200*64][256], rows m=t*64+n: [h2(128)|ctx(128)]
  unsigned* bar_cnt;
  unsigned* bar_rel;
};

__global__ __launch_bounds__(NTH) void k_loop(LA a) {
  const int wg = blockIdx.x, tid = threadIdx.x;

  // ======================= output-projection WGs (64..255) ================
  if (wg >= 64) {
    int o = wg - 64;
    if (o >= 157) return;
    int c0 = o * 64;
    int lane = tid & 63, w4 = tid >> 6;
    int ln15 = lane & 15, lg = lane >> 4, ko = lg * 8;
    for (int t = 0; t < TDEC; ++t) {
      if (tid == 0) {
        unsigned need = 3u * (unsigned)t + 3u;  // L2P(t) done
        while (__hip_atomic_load(a.bar_rel, __ATOMIC_RELAXED,
                                 __HIP_MEMORY_SCOPE_AGENT) < need)
          __builtin_amdgcn_s_sleep(8);
      }
      __syncthreads();
      if (w4 < 4) {
        const __hip_bfloat16* ap =
            a.h2cbf + ((size_t)t * NB + w4 * 16 + ln15) * 256;
        bf16x8 afr[8];
        #pragma unroll
        for (int kk = 0; kk < 8; ++kk) afr[kk] = ldfrag_nt(ap + kk * 32 + ko);
        #pragma unroll
        for (int s = 0; s < 4; ++s) {
          int c = c0 + s * 16 + ln15;
          bool ok = c < VOCAB;
          const __hip_bfloat16* bp = a.Woutbf + (size_t)c * 256;
          f32x4 acc = {0.f, 0.f, 0.f, 0.f};
          #pragma unroll
          for (int kk = 0; kk < 8; ++kk) {
            bf16x8 bv = ok ? ldfrag(bp + kk * 32 + ko) : bf16x8{};
            acc = MFMA16(afr[kk], bv, acc);
          }
          if (ok) {
            float bb = a.bout[c];
            #pragma unroll
            for (int reg = 0; reg < 4; ++reg) {
              int nrow = w4 * 16 + 4 * lg + reg;
              __builtin_nontemporal_store(
                  acc[reg] + bb, &a.out[((size_t)nrow * TDEC + t) * VOCAB + c]);
            }
          }
        }
      }
    }
    return;
  }

  // ======================= recurrence WGs (0..63) =========================
  const int lane = tid & 63, wid = tid >> 6;
  const int ln15 = lane & 15, lg = lane >> 4, ko = lg * 8;
  const int bg = wid & 3, kh = wid >> 2;
  const int d0 = wg * 16;
  const bool inv = (a.big == 0);

  __shared__ float bs1l[16][4];
  __shared__ unsigned short h2tmp[256];
  __shared__ __align__(16) char smem[33792];
  float* part = (float*)smem;            // B:   [4][4][64][4] f32 (16KB)
  float* gl   = (float*)(smem + 16384);  // B:   [4][4][16][16] f32 (16KB)
  float* partL = (float*)smem;           // L2P: [4][64][4] f32 (4KB)
  float* glL   = (float*)(smem + 4096);  // L2P: [4][16][16] f32 (4KB)
  float* h2s  = (float*)smem;            // A: [128] f32
  float* e_l  = (float*)(smem + 2048);   // A: [512] f32
  float* red  = (float*)(smem + 4096);   // A: [512] f32
  float* ctxp = (float*)(smem + 6144);   // A: [8][128] f32

  float creg0 = 0.f, creg1 = 0.f;  // c1 (2 dims/thread, phase B tail)
  float creg2 = 0.f;               // c2 (1 dim/thread, L2P tail, tid<256)

  const __hip_bfloat16 *wb0, *wb1, *wb2, *wb3;
  {
    int g = ln15 & 3, s = ln15 >> 2;
    wb0 = a.W1bf + (size_t)(g * 1024 + d0 + 0 + s) * K1;
    wb1 = a.W1bf + (size_t)(g * 1024 + d0 + 4 + s) * K1;
    wb2 = a.W1bf + (size_t)(g * 1024 + d0 + 8 + s) * K1;
    wb3 = a.W1bf + (size_t)(g * 1024 + d0 + 12 + s) * K1;
  }
  const __hip_bfloat16* w2p =
      a.W2bf + (size_t)((ln15 & 3) * 128 + (wg & 31) * 4 + (ln15 >> 2)) * K2;
  const int nA = bg * 16 + ln15;  // A-operand batch row for this lane
  const int n = wg;               // A: one batch row per WG
  const int len = a.slen[n];

  // -------------------------------- prologue: biases, ctx0 = mean(V)
  if (tid < 64) bs1l[tid >> 2][tid & 3] = a.bsum1[(tid & 3) * 1024 + d0 + (tid >> 2)];
  {
    int v = tid & 127, ph = tid >> 7;  // ph 0..3
    float acc = 0.f;
    if (a.kv) {
      const unsigned short* vb = (const unsigned short*)a.valbf;
      for (int p = ph; p < len; p += 4)
        acc += bf2f(vb[((size_t)n * TENC + p) * VSZ + v]);
    } else {
      for (int p = ph; p < len; p += 4)
        acc += a.value[((size_t)n * TENC + p) * VSZ + v];
    }
    ctxp[ph * 128 + v] = acc;
  }
  __syncthreads();
  if (tid < 64) {
    int vp = tid;
    float invl = 1.f / (float)len;
    float c0 = (ctxp[0 * 128 + 2 * vp] + ctxp[1 * 128 + 2 * vp] +
                ctxp[2 * 128 + 2 * vp] + ctxp[3 * 128 + 2 * vp]) * invl;
    float c1 = (ctxp[0 * 128 + 2 * vp + 1] + ctxp[1 * 128 + 2 * vp + 1] +
                ctxp[2 * 128 + 2 * vp + 1] + ctxp[3 * 128 + 2 * vp + 1]) * invl;
    unsigned pk = pack2bf(c0, c1);
    st_u32_sys(a.ctxr + (size_t)n * 128 + 2 * vp, pk);  // ring slot 0
    st_u32_sys(&a.h2cbf[((size_t)0 * NB + n) * 256 + 128 + 2 * vp], pk);
  }
  int ep = 0;
  gbar(a.bar_cnt, a.bar_rel, ++ep, wg, inv);

  // -------------------------------- main loop
  for (int t = 0; t < TDEC; ++t) {
    const __hip_bfloat16 *h1c, *ctxc;
    __hip_bfloat16 *h1n, *ctxn;
    if (a.big) {
      h1c = a.h1r + (size_t)t * 65536;
      h1n = a.h1r + (size_t)(t + 1) * 65536;
      ctxc = a.ctxr + (size_t)t * 8192;
      ctxn = a.ctxr + (size_t)(t + 1) * 8192;
    } else {
      h1c = a.h1r + (size_t)(t & 1) * 65536;
      h1n = a.h1r + (size_t)((t + 1) & 1) * 65536;
      ctxc = a.ctxr;
      ctxn = a.ctxr;
    }

    // ---------- phase B: LSTM1 (64 WGs; WG owns 16 h1 dims)
    {
      const __hip_bfloat16* ax = a.xembbf + ((size_t)t * NB + nA) * EMBD;
      const __hip_bfloat16* ac = ctxc + nA * 128;
      const __hip_bfloat16* ah = h1c + nA * 1024;
      f32x4 q0 = {0, 0, 0, 0}, q1 = {0, 0, 0, 0}, q2 = {0, 0, 0, 0}, q3 = {0, 0, 0, 0};
      if (kh == 0) {
        #pragma unroll
        for (int s = 0; s < 16; ++s) {
          bf16x8 av = ldfrag(ax + s * 32 + ko);
          int o = s * 32 + ko;
          q0 = MFMA16(av, ldfrag(wb0 + o), q0);
          q1 = MFMA16(av, ldfrag(wb1 + o), q1);
          q2 = MFMA16(av, ldfrag(wb2 + o), q2);
          q3 = MFMA16(av, ldfrag(wb3 + o), q3);
        }
        #pragma unroll
        for (int s = 0; s < 4; ++s) {
          bf16x8 av = ldfrag(ac + s * 32 + ko);
          int o = 512 + s * 32 + ko;
          q0 = MFMA16(av, ldfrag(wb0 + o), q0);
          q1 = MFMA16(av, ldfrag(wb1 + o), q1);
          q2 = MFMA16(av, ldfrag(wb2 + o), q2);
          q3 = MFMA16(av, ldfrag(wb3 + o), q3);
        }
        #pragma unroll
        for (int s = 0; s < 6; ++s) {
          bf16x8 av = ldfrag(ah + s * 32 + ko);
          int o = 640 + s * 32 + ko;
          q0 = MFMA16(av, ldfrag(wb0 + o), q0);
          q1 = MFMA16(av, ldfrag(wb1 + o), q1);
          q2 = MFMA16(av, ldfrag(wb2 + o), q2);
          q3 = MFMA16(av, ldfrag(wb3 + o), q3);
        }
      } else {
        #pragma unroll
        for (int s = 0; s < 26; ++s) {
          bf16x8 av = ldfrag(ah + 192 + s * 32 + ko);
          int o = 832 + s * 32 + ko;
          q0 = MFMA16(av, ldfrag(wb0 + o), q0);
          q1 = MFMA16(av, ldfrag(wb1 + o), q1);
          q2 = MFMA16(av, ldfrag(wb2 + o), q2);
          q3 = MFMA16(av, ldfrag(wb3 + o), q3);
        }
      }
      if (kh == 1) {
        *(f32x4*)&part[(((bg * 4 + 0) * 64) + lane) * 4] = q0;
        *(f32x4*)&part[(((bg * 4 + 1) * 64) + lane) * 4] = q1;
        *(f32x4*)&part[(((bg * 4 + 2) * 64) + lane) * 4] = q2;
        *(f32x4*)&part[(((bg * 4 + 3) * 64) + lane) * 4] = q3;
      }
      __syncthreads();
      if (kh == 0) {
        q0 += *(f32x4*)&part[(((bg * 4 + 0) * 64) + lane) * 4];
        q1 += *(f32x4*)&part[(((bg * 4 + 1) * 64) + lane) * 4];
        q2 += *(f32x4*)&part[(((bg * 4 + 2) * 64) + lane) * 4];
        q3 += *(f32x4*)&part[(((bg * 4 + 3) * 64) + lane) * 4];
        #pragma unroll
        for (int r = 0; r < 4; ++r) {
          gl[((bg * 4 + 0) * 16 + (lg * 4 + r)) * 16 + ln15] = q0[r];
          gl[((bg * 4 + 1) * 16 + (lg * 4 + r)) * 16 + ln15] = q1[r];
          gl[((bg * 4 + 2) * 16 + (lg * 4 + r)) * 16 + ln15] = q2[r];
          gl[((bg * 4 + 3) * 16 + (lg * 4 + r)) * 16 + ln15] = q3[r];
        }
      }
      __syncthreads();
      {  // tail: thread owns (n, dim-pair)
        int nn = tid >> 3, dp = tid & 7;
        int bgg = nn >> 4, ii = nn & 15;
        int t4 = dp >> 1, off = (dp & 1) * 8;
        float* gp = &gl[((bgg * 4 + t4) * 16 + ii) * 16 + off];
        float4 gA = *(float4*)gp;
        float4 gB = *(float4*)(gp + 4);
        int dA = dp * 2, dB = dp * 2 + 1;
        float I = sigm(gA.x + bs1l[dA][0]);
        float F = sigm(gA.y + bs1l[dA][1]);
        float G = ftanh(gA.z + bs1l[dA][2]);
        float O = sigm(gA.w + bs1l[dA][3]);
        float cv = F * creg0 + I * G;
        creg0 = cv;
        float hA = O * ftanh(cv);
        I = sigm(gB.x + bs1l[dB][0]);
        F = sigm(gB.y + bs1l[dB][1]);
        G = ftanh(gB.z + bs1l[dB][2]);
        O = sigm(gB.w + bs1l[dB][3]);
        cv = F * creg1 + I * G;
        creg1 = cv;
        float hB = O * ftanh(cv);
        st_u32_sys(h1n + nn * 1024 + d0 + dA, pack2bf(hA, hB));
      }
    }
    gbar(a.bar_cnt, a.bar_rel, ++ep, wg, inv);

    // ---------- phase L2P: LSTM2 dim-parallel MFMA (WGs 0..31, 4 dims each)
    if (wg < 32) {
      const int e0 = wg * 4;
      const __hip_bfloat16* ah = h1n + nA * 1024;
      f32x4 q = {0.f, 0.f, 0.f, 0.f};
      if (kh == 0) {
        #pragma unroll
        for (int s = 0; s < 18; ++s)
          q = MFMA16(ldfrag(ah + s * 32 + ko), ldfrag(w2p + s * 32 + ko), q);
      } else {
        #pragma unroll
        for (int s = 0; s < 14; ++s)
          q = MFMA16(ldfrag(ah + 576 + s * 32 + ko), ldfrag(w2p + 576 + s * 32 + ko), q);
        if (t > 0) {
          const __hip_bfloat16* hp = a.h2cbf + ((size_t)(t - 1) * NB + nA) * 256;
          #pragma unroll
          for (int s = 0; s < 4; ++s)
            q = MFMA16(ldfrag(hp + s * 32 + ko), ldfrag(w2p + 1024 + s * 32 + ko), q);
        }
      }
      if (kh == 1) *(f32x4*)&partL[(bg * 64 + lane) * 4] = q;
      __syncthreads();
      if (kh == 0) {
        q += *(f32x4*)&partL[(bg * 64 + lane) * 4];
        #pragma unroll
        for (int r = 0; r < 4; ++r)
          glL[(bg * 16 + lg * 4 + r) * 16 + ln15] = q[r];
      }
      __syncthreads();
      if (tid < 256) {
        int n2 = tid >> 2, ds = tid & 3;
        float4 g4 = *(float4*)&glL[((n2 >> 4) * 16 + (n2 & 15)) * 16 + ds * 4];
        int d = e0 + ds;
        float I = sigm(g4.x + a.bsum2[d]);
        float F = sigm(g4.y + a.bsum2[128 + d]);
        float G = ftanh(g4.z + a.bsum2[256 + d]);
        float O = sigm(g4.w + a.bsum2[384 + d]);
        float cv = F * creg2 + I * G;
        creg2 = cv;
        float h = O * ftanh(cv);
        __hip_bfloat16 hb = __float2bfloat16(h);
        h2tmp[n2 * 4 + ds] = *(unsigned short*)&hb;
      }
      __syncthreads();
      if (tid < 128) {
        int n3 = tid >> 1, e = tid & 1;
        unsigned pk = (unsigned)h2tmp[n3 * 4 + 2 * e] |
                      ((unsigned)h2tmp[n3 * 4 + 2 * e + 1] << 16);
        st_u32_sys(&a.h2cbf[((size_t)t * NB + n3) * 256 + e0 + 2 * e], pk);
      }
    }
    gbar(a.bar_cnt, a.bar_rel, ++ep, wg, inv);

    // ---------- phase A: attention (64 WGs, one batch row each)
    if (t < TDEC - 1) {
      if (tid < 64) {  // stage h2(t) row n -> LDS f32
        unsigned u = *(const unsigned*)((const unsigned short*)a.h2cbf +
                                        ((size_t)t * NB + n) * 256 + 2 * tid);
        h2s[2 * tid] = bf2f(u & 0xffffu);
        h2s[2 * tid + 1] = bf2f(u >> 16);
      }
      __syncthreads();
      float e = -INFINITY;
      if (tid < len) {
        float s = 0.f;
        if (a.kv) {
          const uint4* kr = (const uint4*)(a.keybf + ((size_t)n * TENC + tid) * KSZ);
          #pragma unroll
          for (int kk = 0; kk < 16; ++kk) {
            uint4 u = kr[kk];
            const float* hh = &h2s[kk * 8];
            s += bf2f(u.x & 0xffffu) * hh[0] + bf2f(u.x >> 16) * hh[1]
               + bf2f(u.y & 0xffffu) * hh[2] + bf2f(u.y >> 16) * hh[3]
               + bf2f(u.z & 0xffffu) * hh[4] + bf2f(u.z >> 16) * hh[5]
               + bf2f(u.w & 0xffffu) * hh[6] + bf2f(u.w >> 16) * hh[7];
          }
        } else {
          const float4* kr = (const float4*)(a.key + ((size_t)n * TENC + tid) * KSZ);
          #pragma unroll 8
          for (int kk = 0; kk < 32; ++kk) {
            float4 u = kr[kk];
            const float* hh = &h2s[kk * 4];
            s += u.x * hh[0] + u.y * hh[1] + u.z * hh[2] + u.w * hh[3];
          }
        }
        e = s;
      }
      red[tid] = e;
      __syncthreads();
      for (int s2 = 256; s2 > 0; s2 >>= 1) {
        if (tid < s2) red[tid] = fmaxf(red[tid], red[tid + s2]);
        __syncthreads();
      }
      float m = red[0];
      __syncthreads();
      float ex = (tid < len) ? __expf(e - m) : 0.f;
      e_l[tid] = ex;
      red[tid] = ex;
      __syncthreads();
      for (int s2 = 256; s2 > 0; s2 >>= 1) {
        if (tid < s2) red[tid] += red[tid + s2];
        __syncthreads();
      }
      float invs = 1.f / red[0];
      {  // PV: wave w handles p = w, w+8, ...; lanes cover 128 v-dims
        int w = tid >> 6, ln = tid & 63;
        float a0 = 0.f, a1 = 0.f;
        if (a.kv) {
          const unsigned short* vb = (const unsigned short*)a.valbf;
          for (int p = w; p < len; p += 8) {
            unsigned u = *(const unsigned*)(vb + ((size_t)n * TENC + p) * VSZ + 2 * ln);
            float ew = e_l[p];
            a0 += ew * bf2f(u & 0xffffu);
            a1 += ew * bf2f(u >> 16);
          }
        } else {
          for (int p = w; p < len; p += 8) {
            float2 vv = *(const float2*)(a.value + ((size_t)n * TENC + p) * VSZ + 2 * ln);
            float ew = e_l[p];
            a0 += ew * vv.x;
            a1 += ew * vv.y;
          }
        }
        ctxp[w * 128 + 2 * ln] = a0;
        ctxp[w * 128 + 2 * ln + 1] = a1;
      }
      __syncthreads();
      if (tid < 64) {
        int vp = tid;
        float c0 = 0.f, c1 = 0.f;
        #pragma unroll
        for (int w2 = 0; w2 < 8; ++w2) {
          c0 += ctxp[w2 * 128 + 2 * vp];
          c1 += ctxp[w2 * 128 + 2 * vp + 1];
        }
        unsigned pk = pack2bf(c0 * invs, c1 * invs);
        st_u32_sys(ctxn + (size_t)n * 128 + 2 * vp, pk);
        st_u32_sys(&a.h2cbf[((size_t)(t + 1) * NB + n) * 256 + 128 + 2 * vp], pk);
      }
    }
    gbar(a.bar_cnt, a.bar_rel, ++ep, wg, inv);
  }
}

// ---------------------------------------------------------------------------
extern "C" void kernel_launch(void* const* d_in, const int* in_sizes, int n_in,
                              void* d_out, int out_size, void* d_ws, size_t ws_size,
                              hipStream_t stream) {
  (void)in_sizes; (void)n_in; (void)out_size;
  const float* key   = (const float*)d_in[0];
  const float* value = (const float*)d_in[1];
  const int*   slen  = (const int*)d_in[2];
  const int*   text  = (const int*)d_in[3];
  const float* emb   = (const float*)d_in[4];
  const float* Wih1  = (const float*)d_in[5];
  const float* Whh1  = (const float*)d_in[6];
  const float* bih1  = (const float*)d_in[7];
  const float* bhh1  = (const float*)d_in[8];
  const float* Wih2  = (const float*)d_in[9];
  const float* Whh2  = (const float*)d_in[10];
  const float* bih2  = (const float*)d_in[11];
  const float* bhh2  = (const float*)d_in[12];
  const float* Wout  = (const float*)d_in[13];
  const float* bout  = (const float*)d_in[14];
  float* out = (float*)d_out;
  char* ws = (char*)d_ws;

  int big = (ws_size >= BIG_END) ? 1 : 0;
  int kv  = (ws_size >= KV_END) ? 1 : 0;

  __hip_bfloat16* W1bf   = (__hip_bfloat16*)(ws + OFF_W1);
  __hip_bfloat16* W2bf   = (__hip_bfloat16*)(ws + OFF_W2);
  __hip_bfloat16* Woutbf = (__hip_bfloat16*)(ws + OFF_WOUT);
  __hip_bfloat16* xembbf = (__hip_bfloat16*)(ws + OFF_XEMB);
  __hip_bfloat16* h2cbf  = (__hip_bfloat16*)(ws + OFF_H2C);
  float* bsum1 = (float*)(ws + OFF_BS1);
  float* bsum2 = (float*)(ws + OFF_BS2);
  __hip_bfloat16* keybf = (__hip_bfloat16*)(ws + OFF_KEYBF);
  __hip_bfloat16* valbf = (__hip_bfloat16*)(ws + OFF_VALBF);

  hipMemsetAsync(ws, 0, 4096, stream);                 // barrier flags
  hipMemsetAsync(ws + OFF_H1R, 0, 262144, stream);     // h1 ring slots 0,1
  k_prep_w1<<<4096, 256, 0, stream>>>(Wih1, Whh1, bih1, bhh1, W1bf, bsum1);
  k_prep_w2<<<512, 256, 0, stream>>>(Wih2, Whh2, bih2, bhh2, W2bf, bsum2);
  k_prep_wout<<<625, 256, 0, stream>>>(Wout, Woutbf);
  k_gather<<<TDEC, 256, 0, stream>>>(text, emb, xembbf);
  if (kv) k_prep_kv<<<2048, 256, 0, stream>>>(key, value, keybf, valbf);

  LA la;
  la.key = key; la.value = value; la.slen = slen;
  la.keybf = keybf; la.valbf = valbf; la.kv = kv; la.big = big;
  la.W1bf = W1bf; la.W2bf = W2bf; la.Woutbf = Woutbf; la.xembbf = xembbf;
  la.bsum1 = bsum1; la.bsum2 = bsum2; la.bout = bout; la.out = out;
  la.h1r = (__hip_bfloat16*)(ws + OFF_H1R);
  la.ctxr = (__hip_bfloat16*)(ws + OFF_CTXR);
  la.h2cbf = h2cbf;
  la.bar_cnt = (unsigned*)(ws + OFF_BAR);
  la.bar_rel = (unsigned*)(ws + OFF_BAR + 1024);

  void* args[] = {&la};
  hipLaunchCooperativeKernel((void*)k_loop, dim3(NWG), dim3(NTH), args, 0, stream);
}

// Round 10
// 13628.267 us; speedup vs baseline: 2.1361x; 1.0082x over previous
//
#include <hip/hip_runtime.h>
#include <hip/hip_bf16.h>
#include <math.h>

// ---------------------------------------------------------------------------
// Round 10: round 9 with ONE change — out-WGs read h2c with normal cached
// loads instead of nontemporal (NT bypassed L2, forcing 157 re-fetches/step
// of the same 32KB = ~1.0GB of the observed 1.145GB FETCH_SIZE). h2c is
// write-through-stored and each address is written exactly once before any
// read, so cached loads are coherent-safe. NT retained only for `out` stores.
// ---------------------------------------------------------------------------

#define NB    64
#define TENC  500
#define TDEC  200
#define EMBD  512
#define HID   1024
#define KSZ   128
#define VSZ   128
#define VOCAB 10000
#define K1    1664
#define K2    1152
#define NWG   256
#define NTH   512

typedef __bf16 bf16x8 __attribute__((ext_vector_type(8)));
typedef float f32x4 __attribute__((ext_vector_type(4)));
typedef unsigned long long u64;
#define MFMA16(a, b, c) __builtin_amdgcn_mfma_f32_16x16x32_bf16((a), (b), (c), 0, 0, 0)

// ws layout (bytes)
constexpr size_t OFF_BAR   = 0;          // cnt 8x64B + rel u32 @1024
constexpr size_t OFF_BS1   = 4096;       // f32 [4096]
constexpr size_t OFF_BS2   = 20480;      // f32 [512]
constexpr size_t OFF_W2    = 22528;      // bf16 [512][1152] = 1179648
constexpr size_t OFF_H2C   = 1202176;    // bf16 [12800][256] = 6553600
constexpr size_t OFF_W1    = 7755776;    // bf16 [4096][1664] = 13631488
constexpr size_t OFF_WOUT  = 21387264;   // bf16 [10000][256] = 5120000
constexpr size_t OFF_XEMB  = 26507264;   // bf16 [200][64][512] = 13107200
constexpr size_t OFF_H1R   = 39614464;   // bf16 [201][64][1024] = 26345472
constexpr size_t OFF_CTXR  = 65959936;   // bf16 [201][64][128] = 3293184
constexpr size_t BIG_END   = 69253120;
constexpr size_t OFF_KEYBF = 69253120;   // bf16 [64][500][128]
constexpr size_t OFF_VALBF = 77445120;   // bf16 [64][500][128]
constexpr size_t KV_END    = 85637120;

__device__ __forceinline__ float sigm(float x) { return 1.0f / (1.0f + __expf(-x)); }
__device__ __forceinline__ float ftanh(float x) {
  float ax = fabsf(x);
  float e = __expf(2.0f * ax);
  float tv = 1.0f - 2.0f / (e + 1.0f);
  return copysignf(tv, x);
}
__device__ __forceinline__ float bf2f(unsigned u) { return __uint_as_float(u << 16); }
__device__ __forceinline__ bf16x8 ldfrag(const __hip_bfloat16* p) {
  return *reinterpret_cast<const bf16x8*>(p);
}
__device__ __forceinline__ void st_u32_sys(void* p, unsigned v) {
  __hip_atomic_store((unsigned*)p, v, __ATOMIC_RELAXED, __HIP_MEMORY_SCOPE_AGENT);
}
__device__ __forceinline__ unsigned pack2bf(float a, float b) {
  __hip_bfloat16 ha = __float2bfloat16(a), hb = __float2bfloat16(b);
  unsigned short ua = *(unsigned short*)&ha, ub = *(unsigned short*)&hb;
  return (unsigned)ua | ((unsigned)ub << 16);
}

// ------------------------------------------------------------- prep kernels
__global__ __launch_bounds__(256) void k_prep_w1(const float* __restrict__ Wih1,
                                                 const float* __restrict__ Whh1,
                                                 const float* __restrict__ bih1,
                                                 const float* __restrict__ bhh1,
                                                 __hip_bfloat16* __restrict__ W1bf,
                                                 float* __restrict__ bsum1) {
  int r = blockIdx.x;
  const float* wi = Wih1 + (size_t)r * 640;
  const float* wh = Whh1 + (size_t)r * 1024;
  for (int k = threadIdx.x; k < K1; k += 256)
    W1bf[(size_t)r * K1 + k] = __float2bfloat16(k < 640 ? wi[k] : wh[k - 640]);
  if (threadIdx.x == 0) bsum1[r] = bih1[r] + bhh1[r];
}

__global__ __launch_bounds__(256) void k_prep_w2(const float* __restrict__ Wih2,
                                                 const float* __restrict__ Whh2,
                                                 const float* __restrict__ bih2,
                                                 const float* __restrict__ bhh2,
                                                 __hip_bfloat16* __restrict__ W2bf,
                                                 float* __restrict__ bsum2) {
  int r = blockIdx.x;  // 512 rows
  for (int k = threadIdx.x; k < K2; k += 256)
    W2bf[(size_t)r * K2 + k] =
        __float2bfloat16(k < 1024 ? Wih2[(size_t)r * 1024 + k]
                                  : Whh2[(size_t)r * 128 + k - 1024]);
  if (threadIdx.x == 0) bsum2[r] = bih2[r] + bhh2[r];
}

__global__ __launch_bounds__(256) void k_prep_wout(const float* __restrict__ Wout,
                                                   __hip_bfloat16* __restrict__ Woutbf) {
  int r0 = blockIdx.x * 16;
  for (int idx = threadIdx.x; idx < 16 * 256; idx += 256) {
    int r = r0 + (idx >> 8), k = idx & 255;
    Woutbf[(size_t)r * 256 + k] = __float2bfloat16(Wout[(size_t)r * 256 + k]);
  }
}

__global__ __launch_bounds__(256) void k_gather(const int* __restrict__ text,
                                                const float* __restrict__ emb,
                                                __hip_bfloat16* __restrict__ xembbf) {
  int t = blockIdx.x;
  __shared__ int tok[NB];
  if (threadIdx.x < NB) tok[threadIdx.x] = text[threadIdx.x * TDEC + t];
  __syncthreads();
  for (int idx = threadIdx.x; idx < NB * EMBD; idx += 256) {
    int n = idx >> 9, k = idx & 511;
    xembbf[((size_t)t * NB + n) * EMBD + k] =
        __float2bfloat16(emb[(size_t)tok[n] * EMBD + k]);
  }
}

__global__ __launch_bounds__(256) void k_prep_kv(const float* __restrict__ key,
                                                 const float* __restrict__ value,
                                                 __hip_bfloat16* __restrict__ keybf,
                                                 __hip_bfloat16* __restrict__ valbf) {
  int gsz = gridDim.x * 256;
  for (size_t i = blockIdx.x * 256 + threadIdx.x; i < (size_t)NB * TENC * KSZ; i += gsz) {
    keybf[i] = __float2bfloat16(key[i]);
    valbf[i] = __float2bfloat16(value[i]);
  }
}

// ---------------- grid barrier: relaxed (big) or acquire-inv (small)
__device__ __forceinline__ void gbar(unsigned* cnt, unsigned* rel, int ep, int wg,
                                     bool inv) {
  asm volatile("s_waitcnt vmcnt(0)" ::: "memory");
  __syncthreads();
  int tid = threadIdx.x;
  if (tid == 0) {
    if (inv)
      __hip_atomic_fetch_add(&cnt[(wg & 7) << 4], 1u, __ATOMIC_ACQ_REL,
                             __HIP_MEMORY_SCOPE_AGENT);
    else
      __hip_atomic_fetch_add(&cnt[(wg & 7) << 4], 1u, __ATOMIC_RELAXED,
                             __HIP_MEMORY_SCOPE_AGENT);
  }
  if (wg == 0 && tid < 64) {
    unsigned need = (unsigned)ep * 8u;
    for (;;) {
      unsigned v = __hip_atomic_load(&cnt[(tid & 7) << 4], __ATOMIC_RELAXED,
                                     __HIP_MEMORY_SCOPE_AGENT);
      if (__all((int)(v >= need))) break;
      __builtin_amdgcn_s_sleep(1);
    }
    if (inv) {
      unsigned vv = __hip_atomic_load(&cnt[(tid & 7) << 4], __ATOMIC_ACQUIRE,
                                      __HIP_MEMORY_SCOPE_AGENT);
      (void)vv;
    }
    if (tid == 0)
      __hip_atomic_store(rel, (unsigned)ep,
                         inv ? __ATOMIC_RELEASE : __ATOMIC_RELAXED,
                         __HIP_MEMORY_SCOPE_AGENT);
  }
  if (tid == 0) {
    while (__hip_atomic_load(rel, __ATOMIC_RELAXED, __HIP_MEMORY_SCOPE_AGENT) <
           (unsigned)ep)
      __builtin_amdgcn_s_sleep(1);
    if (inv) {
      unsigned rv = __hip_atomic_load(rel, __ATOMIC_ACQUIRE, __HIP_MEMORY_SCOPE_AGENT);
      (void)rv;
    }
  }
  __syncthreads();
}

// ------------------------------------------------------- persistent kernel
struct LA {
  const float* key;
  const float* value;
  const int* slen;
  const __hip_bfloat16* keybf;
  const __hip_bfloat16* valbf;
  int kv;
  int big;
  const __hip_bfloat16* W1bf;
  const __hip_bfloat16* W2bf;
  const __hip_bfloat16* Woutbf;
  const __hip_bfloat16* xembbf;
  const float* bsum1;
  const float* bsum2;
  const float* bout;
  float* out;
  __hip_bfloat16* h1r;    // ring [201][64][1024] (big) / [2][64][1024] (small)
  __hip_bfloat16* ctxr;   // ring [201][64][128]  (big) / [1][64][128]  (small)
  __hip_bfloat16* h2cbf;  // [200*64][256], rows m=t*64+n: [h2(128)|ctx(128)]
  unsigned* bar_cnt;
  unsigned* bar_rel;
};

__global__ __launch_bounds__(NTH) void k_loop(LA a) {
  const int wg = blockIdx.x, tid = threadIdx.x;

  // ======================= output-projection WGs (64..255) ================
  if (wg >= 64) {
    int o = wg - 64;
    if (o >= 157) return;
    int c0 = o * 64;
    int lane = tid & 63, w4 = tid >> 6;
    int ln15 = lane & 15, lg = lane >> 4, ko = lg * 8;
    for (int t = 0; t < TDEC; ++t) {
      if (tid == 0) {
        unsigned need = 3u * (unsigned)t + 3u;  // L2P(t) done
        while (__hip_atomic_load(a.bar_rel, __ATOMIC_RELAXED,
                                 __HIP_MEMORY_SCOPE_AGENT) < need)
          __builtin_amdgcn_s_sleep(8);
      }
      __syncthreads();
      if (w4 < 4) {
        const __hip_bfloat16* ap =
            a.h2cbf + ((size_t)t * NB + w4 * 16 + ln15) * 256;
        bf16x8 afr[8];
        #pragma unroll
        for (int kk = 0; kk < 8; ++kk) afr[kk] = ldfrag(ap + kk * 32 + ko);
        #pragma unroll
        for (int s = 0; s < 4; ++s) {
          int c = c0 + s * 16 + ln15;
          bool ok = c < VOCAB;
          const __hip_bfloat16* bp = a.Woutbf + (size_t)c * 256;
          f32x4 acc = {0.f, 0.f, 0.f, 0.f};
          #pragma unroll
          for (int kk = 0; kk < 8; ++kk) {
            bf16x8 bv = ok ? ldfrag(bp + kk * 32 + ko) : bf16x8{};
            acc = MFMA16(afr[kk], bv, acc);
          }
          if (ok) {
            float bb = a.bout[c];
            #pragma unroll
            for (int reg = 0; reg < 4; ++reg) {
              int nrow = w4 * 16 + 4 * lg + reg;
              __builtin_nontemporal_store(
                  acc[reg] + bb, &a.out[((size_t)nrow * TDEC + t) * VOCAB + c]);
            }
          }
        }
      }
    }
    return;
  }

  // ======================= recurrence WGs (0..63) =========================
  const int lane = tid & 63, wid = tid >> 6;
  const int ln15 = lane & 15, lg = lane >> 4, ko = lg * 8;
  const int bg = wid & 3, kh = wid >> 2;
  const int d0 = wg * 16;
  const bool inv = (a.big == 0);

  __shared__ float bs1l[16][4];
  __shared__ unsigned short h2tmp[256];
  __shared__ __align__(16) char smem[33792];
  float* part = (float*)smem;            // B:   [4][4][64][4] f32 (16KB)
  float* gl   = (float*)(smem + 16384);  // B:   [4][4][16][16] f32 (16KB)
  float* partL = (float*)smem;           // L2P: [4][64][4] f32 (4KB)
  float* glL   = (float*)(smem + 4096);  // L2P: [4][16][16] f32 (4KB)
  float* h2s  = (float*)smem;            // A: [128] f32
  float* e_l  = (float*)(smem + 2048);   // A: [512] f32
  float* red  = (float*)(smem + 4096);   // A: [512] f32
  float* ctxp = (float*)(smem + 6144);   // A: [8][128] f32

  float creg0 = 0.f, creg1 = 0.f;  // c1 (2 dims/thread, phase B tail)
  float creg2 = 0.f;               // c2 (1 dim/thread, L2P tail, tid<256)

  const __hip_bfloat16 *wb0, *wb1, *wb2, *wb3;
  {
    int g = ln15 & 3, s = ln15 >> 2;
    wb0 = a.W1bf + (size_t)(g * 1024 + d0 + 0 + s) * K1;
    wb1 = a.W1bf + (size_t)(g * 1024 + d0 + 4 + s) * K1;
    wb2 = a.W1bf + (size_t)(g * 1024 + d0 + 8 + s) * K1;
    wb3 = a.W1bf + (size_t)(g * 1024 + d0 + 12 + s) * K1;
  }
  const __hip_bfloat16* w2p =
      a.W2bf + (size_t)((ln15 & 3) * 128 + (wg & 31) * 4 + (ln15 >> 2)) * K2;
  const int nA = bg * 16 + ln15;  // A-operand batch row for this lane
  const int n = wg;               // A: one batch row per WG
  const int len = a.slen[n];

  // -------------------------------- prologue: biases, ctx0 = mean(V)
  if (tid < 64) bs1l[tid >> 2][tid & 3] = a.bsum1[(tid & 3) * 1024 + d0 + (tid >> 2)];
  {
    int v = tid & 127, ph = tid >> 7;  // ph 0..3
    float acc = 0.f;
    if (a.kv) {
      const unsigned short* vb = (const unsigned short*)a.valbf;
      for (int p = ph; p < len; p += 4)
        acc += bf2f(vb[((size_t)n * TENC + p) * VSZ + v]);
    } else {
      for (int p = ph; p < len; p += 4)
        acc += a.value[((size_t)n * TENC + p) * VSZ + v];
    }
    ctxp[ph * 128 + v] = acc;
  }
  __syncthreads();
  if (tid < 64) {
    int vp = tid;
    float invl = 1.f / (float)len;
    float c0 = (ctxp[0 * 128 + 2 * vp] + ctxp[1 * 128 + 2 * vp] +
                ctxp[2 * 128 + 2 * vp] + ctxp[3 * 128 + 2 * vp]) * invl;
    float c1 = (ctxp[0 * 128 + 2 * vp + 1] + ctxp[1 * 128 + 2 * vp + 1] +
                ctxp[2 * 128 + 2 * vp + 1] + ctxp[3 * 128 + 2 * vp + 1]) * invl;
    unsigned pk = pack2bf(c0, c1);
    st_u32_sys(a.ctxr + (size_t)n * 128 + 2 * vp, pk);  // ring slot 0
    st_u32_sys(&a.h2cbf[((size_t)0 * NB + n) * 256 + 128 + 2 * vp], pk);
  }
  int ep = 0;
  gbar(a.bar_cnt, a.bar_rel, ++ep, wg, inv);

  // -------------------------------- main loop
  for (int t = 0; t < TDEC; ++t) {
    const __hip_bfloat16 *h1c, *ctxc;
    __hip_bfloat16 *h1n, *ctxn;
    if (a.big) {
      h1c = a.h1r + (size_t)t * 65536;
      h1n = a.h1r + (size_t)(t + 1) * 65536;
      ctxc = a.ctxr + (size_t)t * 8192;
      ctxn = a.ctxr + (size_t)(t + 1) * 8192;
    } else {
      h1c = a.h1r + (size_t)(t & 1) * 65536;
      h1n = a.h1r + (size_t)((t + 1) & 1) * 65536;
      ctxc = a.ctxr;
      ctxn = a.ctxr;
    }

    // ---------- phase B: LSTM1 (64 WGs; WG owns 16 h1 dims)
    {
      const __hip_bfloat16* ax = a.xembbf + ((size_t)t * NB + nA) * EMBD;
      const __hip_bfloat16* ac = ctxc + nA * 128;
      const __hip_bfloat16* ah = h1c + nA * 1024;
      f32x4 q0 = {0, 0, 0, 0}, q1 = {0, 0, 0, 0}, q2 = {0, 0, 0, 0}, q3 = {0, 0, 0, 0};
      if (kh == 0) {
        #pragma unroll
        for (int s = 0; s < 16; ++s) {
          bf16x8 av = ldfrag(ax + s * 32 + ko);
          int o = s * 32 + ko;
          q0 = MFMA16(av, ldfrag(wb0 + o), q0);
          q1 = MFMA16(av, ldfrag(wb1 + o), q1);
          q2 = MFMA16(av, ldfrag(wb2 + o), q2);
          q3 = MFMA16(av, ldfrag(wb3 + o), q3);
        }
        #pragma unroll
        for (int s = 0; s < 4; ++s) {
          bf16x8 av = ldfrag(ac + s * 32 + ko);
          int o = 512 + s * 32 + ko;
          q0 = MFMA16(av, ldfrag(wb0 + o), q0);
          q1 = MFMA16(av, ldfrag(wb1 + o), q1);
          q2 = MFMA16(av, ldfrag(wb2 + o), q2);
          q3 = MFMA16(av, ldfrag(wb3 + o), q3);
        }
        #pragma unroll
        for (int s = 0; s < 6; ++s) {
          bf16x8 av = ldfrag(ah + s * 32 + ko);
          int o = 640 + s * 32 + ko;
          q0 = MFMA16(av, ldfrag(wb0 + o), q0);
          q1 = MFMA16(av, ldfrag(wb1 + o), q1);
          q2 = MFMA16(av, ldfrag(wb2 + o), q2);
          q3 = MFMA16(av, ldfrag(wb3 + o), q3);
        }
      } else {
        #pragma unroll
        for (int s = 0; s < 26; ++s) {
          bf16x8 av = ldfrag(ah + 192 + s * 32 + ko);
          int o = 832 + s * 32 + ko;
          q0 = MFMA16(av, ldfrag(wb0 + o), q0);
          q1 = MFMA16(av, ldfrag(wb1 + o), q1);
          q2 = MFMA16(av, ldfrag(wb2 + o), q2);
          q3 = MFMA16(av, ldfrag(wb3 + o), q3);
        }
      }
      if (kh == 1) {
        *(f32x4*)&part[(((bg * 4 + 0) * 64) + lane) * 4] = q0;
        *(f32x4*)&part[(((bg * 4 + 1) * 64) + lane) * 4] = q1;
        *(f32x4*)&part[(((bg * 4 + 2) * 64) + lane) * 4] = q2;
        *(f32x4*)&part[(((bg * 4 + 3) * 64) + lane) * 4] = q3;
      }
      __syncthreads();
      if (kh == 0) {
        q0 += *(f32x4*)&part[(((bg * 4 + 0) * 64) + lane) * 4];
        q1 += *(f32x4*)&part[(((bg * 4 + 1) * 64) + lane) * 4];
        q2 += *(f32x4*)&part[(((bg * 4 + 2) * 64) + lane) * 4];
        q3 += *(f32x4*)&part[(((bg * 4 + 3) * 64) + lane) * 4];
        #pragma unroll
        for (int r = 0; r < 4; ++r) {
          gl[((bg * 4 + 0) * 16 + (lg * 4 + r)) * 16 + ln15] = q0[r];
          gl[((bg * 4 + 1) * 16 + (lg * 4 + r)) * 16 + ln15] = q1[r];
          gl[((bg * 4 + 2) * 16 + (lg * 4 + r)) * 16 + ln15] = q2[r];
          gl[((bg * 4 + 3) * 16 + (lg * 4 + r)) * 16 + ln15] = q3[r];
        }
      }
      __syncthreads();
      {  // tail: thread owns (n, dim-pair)
        int nn = tid >> 3, dp = tid & 7;
        int bgg = nn >> 4, ii = nn & 15;
        int t4 = dp >> 1, off = (dp & 1) * 8;
        float* gp = &gl[((bgg * 4 + t4) * 16 + ii) * 16 + off];
        float4 gA = *(float4*)gp;
        float4 gB = *(float4*)(gp + 4);
        int dA = dp * 2, dB = dp * 2 + 1;
        float I = sigm(gA.x + bs1l[dA][0]);
        float F = sigm(gA.y + bs1l[dA][1]);
        float G = ftanh(gA.z + bs1l[dA][2]);
        float O = sigm(gA.w + bs1l[dA][3]);
        float cv = F * creg0 + I * G;
        creg0 = cv;
        float hA = O * ftanh(cv);
        I = sigm(gB.x + bs1l[dB][0]);
        F = sigm(gB.y + bs1l[dB][1]);
        G = ftanh(gB.z + bs1l[dB][2]);
        O = sigm(gB.w + bs1l[dB][3]);
        cv = F * creg1 + I * G;
        creg1 = cv;
        float hB = O * ftanh(cv);
        st_u32_sys(h1n + nn * 1024 + d0 + dA, pack2bf(hA, hB));
      }
    }
    gbar(a.bar_cnt, a.bar_rel, ++ep, wg, inv);

    // ---------- phase L2P: LSTM2 dim-parallel MFMA (WGs 0..31, 4 dims each)
    if (wg < 32) {
      const int e0 = wg * 4;
      const __hip_bfloat16* ah = h1n + nA * 1024;
      f32x4 q = {0.f, 0.f, 0.f, 0.f};
      if (kh == 0) {
        #pragma unroll
        for (int s = 0; s < 18; ++s)
          q = MFMA16(ldfrag(ah + s * 32 + ko), ldfrag(w2p + s * 32 + ko), q);
      } else {
        #pragma unroll
        for (int s = 0; s < 14; ++s)
          q = MFMA16(ldfrag(ah + 576 + s * 32 + ko), ldfrag(w2p + 576 + s * 32 + ko), q);
        if (t > 0) {
          const __hip_bfloat16* hp = a.h2cbf + ((size_t)(t - 1) * NB + nA) * 256;
          #pragma unroll
          for (int s = 0; s < 4; ++s)
            q = MFMA16(ldfrag(hp + s * 32 + ko), ldfrag(w2p + 1024 + s * 32 + ko), q);
        }
      }
      if (kh == 1) *(f32x4*)&partL[(bg * 64 + lane) * 4] = q;
      __syncthreads();
      if (kh == 0) {
        q += *(f32x4*)&partL[(bg * 64 + lane) * 4];
        #pragma unroll
        for (int r = 0; r < 4; ++r)
          glL[(bg * 16 + lg * 4 + r) * 16 + ln15] = q[r];
      }
      __syncthreads();
      if (tid < 256) {
        int n2 = tid >> 2, ds = tid & 3;
        float4 g4 = *(float4*)&glL[((n2 >> 4) * 16 + (n2 & 15)) * 16 + ds * 4];
        int d = e0 + ds;
        float I = sigm(g4.x + a.bsum2[d]);
        float F = sigm(g4.y + a.bsum2[128 + d]);
        float G = ftanh(g4.z + a.bsum2[256 + d]);
        float O = sigm(g4.w + a.bsum2[384 + d]);
        float cv = F * creg2 + I * G;
        creg2 = cv;
        float h = O * ftanh(cv);
        __hip_bfloat16 hb = __float2bfloat16(h);
        h2tmp[n2 * 4 + ds] = *(unsigned short*)&hb;
      }
      __syncthreads();
      if (tid < 128) {
        int n3 = tid >> 1, e = tid & 1;
        unsigned pk = (unsigned)h2tmp[n3 * 4 + 2 * e] |
                      ((unsigned)h2tmp[n3 * 4 + 2 * e + 1] << 16);
        st_u32_sys(&a.h2cbf[((size_t)t * NB + n3) * 256 + e0 + 2 * e], pk);
      }
    }
    gbar(a.bar_cnt, a.bar_rel, ++ep, wg, inv);

    // ---------- phase A: attention (64 WGs, one batch row each)
    if (t < TDEC - 1) {
      if (tid < 64) {  // stage h2(t) row n -> LDS f32
        unsigned u = *(const unsigned*)((const unsigned short*)a.h2cbf +
                                        ((size_t)t * NB + n) * 256 + 2 * tid);
        h2s[2 * tid] = bf2f(u & 0xffffu);
        h2s[2 * tid + 1] = bf2f(u >> 16);
      }
      __syncthreads();
      float e = -INFINITY;
      if (tid < len) {
        float s = 0.f;
        if (a.kv) {
          const uint4* kr = (const uint4*)(a.keybf + ((size_t)n * TENC + tid) * KSZ);
          #pragma unroll
          for (int kk = 0; kk < 16; ++kk) {
            uint4 u = kr[kk];
            const float* hh = &h2s[kk * 8];
            s += bf2f(u.x & 0xffffu) * hh[0] + bf2f(u.x >> 16) * hh[1]
               + bf2f(u.y & 0xffffu) * hh[2] + bf2f(u.y >> 16) * hh[3]
               + bf2f(u.z & 0xffffu) * hh[4] + bf2f(u.z >> 16) * hh[5]
               + bf2f(u.w & 0xffffu) * hh[6] + bf2f(u.w >> 16) * hh[7];
          }
        } else {
          const float4* kr = (const float4*)(a.key + ((size_t)n * TENC + tid) * KSZ);
          #pragma unroll 8
          for (int kk = 0; kk < 32; ++kk) {
            float4 u = kr[kk];
            const float* hh = &h2s[kk * 4];
            s += u.x * hh[0] + u.y * hh[1] + u.z * hh[2] + u.w * hh[3];
          }
        }
        e = s;
      }
      red[tid] = e;
      __syncthreads();
      for (int s2 = 256; s2 > 0; s2 >>= 1) {
        if (tid < s2) red[tid] = fmaxf(red[tid], red[tid + s2]);
        __syncthreads();
      }
      float m = red[0];
      __syncthreads();
      float ex = (tid < len) ? __expf(e - m) : 0.f;
      e_l[tid] = ex;
      red[tid] = ex;
      __syncthreads();
      for (int s2 = 256; s2 > 0; s2 >>= 1) {
        if (tid < s2) red[tid] += red[tid + s2];
        __syncthreads();
      }
      float invs = 1.f / red[0];
      {  // PV: wave w handles p = w, w+8, ...; lanes cover 128 v-dims
        int w = tid >> 6, ln = tid & 63;
        float a0 = 0.f, a1 = 0.f;
        if (a.kv) {
          const unsigned short* vb = (const unsigned short*)a.valbf;
          for (int p = w; p < len; p += 8) {
            unsigned u = *(const unsigned*)(vb + ((size_t)n * TENC + p) * VSZ + 2 * ln);
            float ew = e_l[p];
            a0 += ew * bf2f(u & 0xffffu);
            a1 += ew * bf2f(u >> 16);
          }
        } else {
          for (int p = w; p < len; p += 8) {
            float2 vv = *(const float2*)(a.value + ((size_t)n * TENC + p) * VSZ + 2 * ln);
            float ew = e_l[p];
            a0 += ew * vv.x;
            a1 += ew * vv.y;
          }
        }
        ctxp[w * 128 + 2 * ln] = a0;
        ctxp[w * 128 + 2 * ln + 1] = a1;
      }
      __syncthreads();
      if (tid < 64) {
        int vp = tid;
        float c0 = 0.f, c1 = 0.f;
        #pragma unroll
        for (int w2 = 0; w2 < 8; ++w2) {
          c0 += ctxp[w2 * 128 + 2 * vp];
          c1 += ctxp[w2 * 128 + 2 * vp + 1];
        }
        unsigned pk = pack2bf(c0 * invs, c1 * invs);
        st_u32_sys(ctxn + (size_t)n * 128 + 2 * vp, pk);
        st_u32_sys(&a.h2cbf[((size_t)(t + 1) * NB + n) * 256 + 128 + 2 * vp], pk);
      }
    }
    gbar(a.bar_cnt, a.bar_rel, ++ep, wg, inv);
  }
}

// ---------------------------------------------------------------------------
extern "C" void kernel_launch(void* const* d_in, const int* in_sizes, int n_in,
                              void* d_out, int out_size, void* d_ws, size_t ws_size,
                              hipStream_t stream) {
  (void)in_sizes; (void)n_in; (void)out_size;
  const float* key   = (const float*)d_in[0];
  const float* value = (const float*)d_in[1];
  const int*   slen  = (const int*)d_in[2];
  const int*   text  = (const int*)d_in[3];
  const float* emb   = (const float*)d_in[4];
  const float* Wih1  = (const float*)d_in[5];
  const float* Whh1  = (const float*)d_in[6];
  const float* bih1  = (const float*)d_in[7];
  const float* bhh1  = (const float*)d_in[8];
  const float* Wih2  = (const float*)d_in[9];
  const float* Whh2  = (const float*)d_in[10];
  const float* bih2  = (const float*)d_in[11];
  const float* bhh2  = (const float*)d_in[12];
  const float* Wout  = (const float*)d_in[13];
  const float* bout  = (const float*)d_in[14];
  float* out = (float*)d_out;
  char* ws = (char*)d_ws;

  int big = (ws_size >= BIG_END) ? 1 : 0;
  int kv  = (ws_size >= KV_END) ? 1 : 0;

  __hip_bfloat16* W1bf   = (__hip_bfloat16*)(ws + OFF_W1);
  __hip_bfloat16* W2bf   = (__hip_bfloat16*)(ws + OFF_W2);
  __hip_bfloat16* Woutbf = (__hip_bfloat16*)(ws + OFF_WOUT);
  __hip_bfloat16* xembbf = (__hip_bfloat16*)(ws + OFF_XEMB);
  __hip_bfloat16* h2cbf  = (__hip_bfloat16*)(ws + OFF_H2C);
  float* bsum1 = (float*)(ws + OFF_BS1);
  float* bsum2 = (float*)(ws + OFF_BS2);
  __hip_bfloat16* keybf = (__hip_bfloat16*)(ws + OFF_KEYBF);
  __hip_bfloat16* valbf = (__hip_bfloat16*)(ws + OFF_VALBF);

  hipMemsetAsync(ws, 0, 4096, stream);                 // barrier flags
  hipMemsetAsync(ws + OFF_H1R, 0, 262144, stream);     // h1 ring slots 0,1
  k_prep_w1<<<4096, 256, 0, stream>>>(Wih1, Whh1, bih1, bhh1, W1bf, bsum1);
  k_prep_w2<<<512, 256, 0, stream>>>(Wih2, Whh2, bih2, bhh2, W2bf, bsum2);
  k_prep_wout<<<625, 256, 0, stream>>>(Wout, Woutbf);
  k_gather<<<TDEC, 256, 0, stream>>>(text, emb, xembbf);
  if (kv) k_prep_kv<<<2048, 256, 0, stream>>>(key, value, keybf, valbf);

  LA la;
  la.key = key; la.value = value; la.slen = slen;
  la.keybf = keybf; la.valbf = valbf; la.kv = kv; la.big = big;
  la.W1bf = W1bf; la.W2bf = W2bf; la.Woutbf = Woutbf; la.xembbf = xembbf;
  la.bsum1 = bsum1; la.bsum2 = bsum2; la.bout = bout; la.out = out;
  la.h1r = (__hip_bfloat16*)(ws + OFF_H1R);
  la.ctxr = (__hip_bfloat16*)(ws + OFF_CTXR);
  la.h2cbf = h2cbf;
  la.bar_cnt = (unsigned*)(ws + OFF_BAR);
  la.bar_rel = (unsigned*)(ws + OFF_BAR + 1024);

  void* args[] = {&la};
  hipLaunchCooperativeKernel((void*)k_loop, dim3(NWG), dim3(NTH), args, 0, stream);
}

// Round 11
// 12119.498 us; speedup vs baseline: 2.4020x; 1.1245x over previous
//
#include <hip/hip_runtime.h>
#include <hip/hip_bf16.h>
#include <math.h>

// ---------------------------------------------------------------------------
// Round 11: r10 + (1) attention split across main WG n [0,250) and helper WG
// n+64 [250,len) with exact online-softmax merge via per-row flag handshake
// (helper publishes m,S,P write-through; main reads via L2-bypassing relaxed
// atomics). Same-XCD pairing keeps KV residency, halves read latency.
// (2) Wout reads in out-WGs (now 128..255) are NONTEMPORAL: frees ~640KB/XCD
// L2 so KV (2MB/XCD) + W1 (1.7MB) fit under 4MB -> kills the ~1.2GB KV
// re-fetch stream (r7 control showed FETCH is recurrence-side, not out-side).
// ---------------------------------------------------------------------------

#define NB    64
#define TENC  500
#define TDEC  200
#define EMBD  512
#define HID   1024
#define KSZ   128
#define VSZ   128
#define VOCAB 10000
#define K1    1664
#define K2    1152
#define NWG   256
#define NTH   512

typedef __bf16 bf16x8 __attribute__((ext_vector_type(8)));
typedef float f32x4 __attribute__((ext_vector_type(4)));
typedef unsigned long long u64;
#define MFMA16(a, b, c) __builtin_amdgcn_mfma_f32_16x16x32_bf16((a), (b), (c), 0, 0, 0)

// ws layout (bytes)
constexpr size_t OFF_BAR   = 0;          // cnt 8x64B @0, rel @1024, ms @2048, flags @2560
constexpr size_t OFF_BS1   = 4096;       // f32 [4096]
constexpr size_t OFF_BS2   = 20480;      // f32 [512]
constexpr size_t OFF_W2    = 22528;      // bf16 [512][1152] = 1179648
constexpr size_t OFF_H2C   = 1202176;    // bf16 [12800][256] = 6553600
constexpr size_t OFF_W1    = 7755776;    // bf16 [4096][1664] = 13631488
constexpr size_t OFF_WOUT  = 21387264;   // bf16 [10000][256] = 5120000
constexpr size_t OFF_XEMB  = 26507264;   // bf16 [200][64][512] = 13107200
constexpr size_t OFF_H1R   = 39614464;   // bf16 [201][64][1024] = 26345472
constexpr size_t OFF_CTXR  = 65959936;   // bf16 [201][64][128]; slot 200 = helper P buf
constexpr size_t BIG_END   = 69253120;
constexpr size_t OFF_KEYBF = 69253120;   // bf16 [64][500][128]
constexpr size_t OFF_VALBF = 77445120;   // bf16 [64][500][128]
constexpr size_t KV_END    = 85637120;

__device__ __forceinline__ float sigm(float x) { return 1.0f / (1.0f + __expf(-x)); }
__device__ __forceinline__ float ftanh(float x) {
  float ax = fabsf(x);
  float e = __expf(2.0f * ax);
  float tv = 1.0f - 2.0f / (e + 1.0f);
  return copysignf(tv, x);
}
__device__ __forceinline__ float bf2f(unsigned u) { return __uint_as_float(u << 16); }
__device__ __forceinline__ bf16x8 ldfrag(const __hip_bfloat16* p) {
  return *reinterpret_cast<const bf16x8*>(p);
}
__device__ __forceinline__ bf16x8 ldfrag_nt(const __hip_bfloat16* p) {
  union { u64 u[2]; bf16x8 v; } r;
  r.u[0] = __builtin_nontemporal_load((const u64*)p);
  r.u[1] = __builtin_nontemporal_load((const u64*)(p + 4));
  return r.v;
}
__device__ __forceinline__ void st_u32_sys(void* p, unsigned v) {
  __hip_atomic_store((unsigned*)p, v, __ATOMIC_RELAXED, __HIP_MEMORY_SCOPE_AGENT);
}
__device__ __forceinline__ unsigned ld_u32_sys(const void* p) {
  return __hip_atomic_load((const unsigned*)p, __ATOMIC_RELAXED, __HIP_MEMORY_SCOPE_AGENT);
}
__device__ __forceinline__ unsigned pack2bf(float a, float b) {
  __hip_bfloat16 ha = __float2bfloat16(a), hb = __float2bfloat16(b);
  unsigned short ua = *(unsigned short*)&ha, ub = *(unsigned short*)&hb;
  return (unsigned)ua | ((unsigned)ub << 16);
}

// ------------------------------------------------------------- prep kernels
__global__ __launch_bounds__(256) void k_prep_w1(const float* __restrict__ Wih1,
                                                 const float* __restrict__ Whh1,
                                                 const float* __restrict__ bih1,
                                                 const float* __restrict__ bhh1,
                                                 __hip_bfloat16* __restrict__ W1bf,
                                                 float* __restrict__ bsum1) {
  int r = blockIdx.x;
  const float* wi = Wih1 + (size_t)r * 640;
  const float* wh = Whh1 + (size_t)r * 1024;
  for (int k = threadIdx.x; k < K1; k += 256)
    W1bf[(size_t)r * K1 + k] = __float2bfloat16(k < 640 ? wi[k] : wh[k - 640]);
  if (threadIdx.x == 0) bsum1[r] = bih1[r] + bhh1[r];
}

__global__ __launch_bounds__(256) void k_prep_w2(const float* __restrict__ Wih2,
                                                 const float* __restrict__ Whh2,
                                                 const float* __restrict__ bih2,
                                                 const float* __restrict__ bhh2,
                                                 __hip_bfloat16* __restrict__ W2bf,
                                                 float* __restrict__ bsum2) {
  int r = blockIdx.x;  // 512 rows
  for (int k = threadIdx.x; k < K2; k += 256)
    W2bf[(size_t)r * K2 + k] =
        __float2bfloat16(k < 1024 ? Wih2[(size_t)r * 1024 + k]
                                  : Whh2[(size_t)r * 128 + k - 1024]);
  if (threadIdx.x == 0) bsum2[r] = bih2[r] + bhh2[r];
}

__global__ __launch_bounds__(256) void k_prep_wout(const float* __restrict__ Wout,
                                                   __hip_bfloat16* __restrict__ Woutbf) {
  int r0 = blockIdx.x * 16;
  for (int idx = threadIdx.x; idx < 16 * 256; idx += 256) {
    int r = r0 + (idx >> 8), k = idx & 255;
    Woutbf[(size_t)r * 256 + k] = __float2bfloat16(Wout[(size_t)r * 256 + k]);
  }
}

__global__ __launch_bounds__(256) void k_gather(const int* __restrict__ text,
                                                const float* __restrict__ emb,
                                                __hip_bfloat16* __restrict__ xembbf) {
  int t = blockIdx.x;
  __shared__ int tok[NB];
  if (threadIdx.x < NB) tok[threadIdx.x] = text[threadIdx.x * TDEC + t];
  __syncthreads();
  for (int idx = threadIdx.x; idx < NB * EMBD; idx += 256) {
    int n = idx >> 9, k = idx & 511;
    xembbf[((size_t)t * NB + n) * EMBD + k] =
        __float2bfloat16(emb[(size_t)tok[n] * EMBD + k]);
  }
}

__global__ __launch_bounds__(256) void k_prep_kv(const float* __restrict__ key,
                                                 const float* __restrict__ value,
                                                 __hip_bfloat16* __restrict__ keybf,
                                                 __hip_bfloat16* __restrict__ valbf) {
  int gsz = gridDim.x * 256;
  for (size_t i = blockIdx.x * 256 + threadIdx.x; i < (size_t)NB * TENC * KSZ; i += gsz) {
    keybf[i] = __float2bfloat16(key[i]);
    valbf[i] = __float2bfloat16(value[i]);
  }
}

// ---------------- grid barrier: relaxed (big) or acquire-inv (small)
__device__ __forceinline__ void gbar(unsigned* cnt, unsigned* rel, int ep, int wg,
                                     bool inv) {
  asm volatile("s_waitcnt vmcnt(0)" ::: "memory");
  __syncthreads();
  int tid = threadIdx.x;
  if (tid == 0) {
    if (inv)
      __hip_atomic_fetch_add(&cnt[(wg & 7) << 4], 1u, __ATOMIC_ACQ_REL,
                             __HIP_MEMORY_SCOPE_AGENT);
    else
      __hip_atomic_fetch_add(&cnt[(wg & 7) << 4], 1u, __ATOMIC_RELAXED,
                             __HIP_MEMORY_SCOPE_AGENT);
  }
  if (wg == 0 && tid < 64) {
    unsigned need = (unsigned)ep * 8u;
    for (;;) {
      unsigned v = __hip_atomic_load(&cnt[(tid & 7) << 4], __ATOMIC_RELAXED,
                                     __HIP_MEMORY_SCOPE_AGENT);
      if (__all((int)(v >= need))) break;
      __builtin_amdgcn_s_sleep(1);
    }
    if (inv) {
      unsigned vv = __hip_atomic_load(&cnt[(tid & 7) << 4], __ATOMIC_ACQUIRE,
                                      __HIP_MEMORY_SCOPE_AGENT);
      (void)vv;
    }
    if (tid == 0)
      __hip_atomic_store(rel, (unsigned)ep,
                         inv ? __ATOMIC_RELEASE : __ATOMIC_RELAXED,
                         __HIP_MEMORY_SCOPE_AGENT);
  }
  if (tid == 0) {
    while (__hip_atomic_load(rel, __ATOMIC_RELAXED, __HIP_MEMORY_SCOPE_AGENT) <
           (unsigned)ep)
      __builtin_amdgcn_s_sleep(1);
    if (inv) {
      unsigned rv = __hip_atomic_load(rel, __ATOMIC_ACQUIRE, __HIP_MEMORY_SCOPE_AGENT);
      (void)rv;
    }
  }
  __syncthreads();
}

// ------------------------------------------------------- persistent kernel
struct LA {
  const float* key;
  const float* value;
  const int* slen;
  const __hip_bfloat16* keybf;
  const __hip_bfloat16* valbf;
  int kv;
  int big;
  const __hip_bfloat16* W1bf;
  const __hip_bfloat16* W2bf;
  const __hip_bfloat16* Woutbf;
  const __hip_bfloat16* xembbf;
  const float* bsum1;
  const float* bsum2;
  const float* bout;
  float* out;
  __hip_bfloat16* h1r;    // ring [201][64][1024] (big) / [2][64][1024] (small)
  __hip_bfloat16* ctxr;   // ring [201][64][128]
  __hip_bfloat16* h2cbf;  // [200*64][256]
  __hip_bfloat16* pbuf;   // helper P partials [64][128] (ctxr slot 200)
  unsigned* ms;           // helper m,S [64][2] (f32 bits)
  unsigned* flags;        // helper flags [64]
  unsigned* bar_cnt;
  unsigned* bar_rel;
};

__global__ __launch_bounds__(NTH) void k_loop(LA a) {
  const int wg = blockIdx.x, tid = threadIdx.x;

  __shared__ float bs1l[16][4];
  __shared__ unsigned short h2tmp[256];
  __shared__ __align__(16) char smem[33792];
  float* part = (float*)smem;            // B:   [4][4][64][4] f32 (16KB)
  float* gl   = (float*)(smem + 16384);  // B:   [4][4][16][16] f32 (16KB)
  float* partL = (float*)smem;           // L2P: [4][64][4] f32 (4KB)
  float* glL   = (float*)(smem + 4096);  // L2P: [4][16][16] f32 (4KB)
  float* h2s  = (float*)smem;            // A: [128] f32
  float* e_l  = (float*)(smem + 2048);   // A: [512] f32
  float* red  = (float*)(smem + 4096);   // A: [512] f32
  float* ctxp = (float*)(smem + 6144);   // A: [8][128] f32

  // ======================= output-projection WGs (128..255) ===============
  if (wg >= 128) {
    int o0 = wg - 128;
    int lane = tid & 63, w4 = tid >> 6;
    int ln15 = lane & 15, lg = lane >> 4, ko = lg * 8;
    for (int t = 0; t < TDEC; ++t) {
      if (tid == 0) {
        unsigned need = 3u * (unsigned)t + 3u;  // L2P(t) done
        while (__hip_atomic_load(a.bar_rel, __ATOMIC_RELAXED,
                                 __HIP_MEMORY_SCOPE_AGENT) < need)
          __builtin_amdgcn_s_sleep(8);
      }
      __syncthreads();
      if (w4 < 4) {
        const __hip_bfloat16* ap =
            a.h2cbf + ((size_t)t * NB + w4 * 16 + ln15) * 256;
        bf16x8 afr[8];
        #pragma unroll
        for (int kk = 0; kk < 8; ++kk) afr[kk] = ldfrag(ap + kk * 32 + ko);
        for (int sub = 0; sub < 2; ++sub) {
          int o = o0 + sub * 128;
          if (o >= 157) break;
          int c0 = o * 64;
          #pragma unroll
          for (int s = 0; s < 4; ++s) {
            int c = c0 + s * 16 + ln15;
            bool ok = c < VOCAB;
            const __hip_bfloat16* bp = a.Woutbf + (size_t)c * 256;
            f32x4 acc = {0.f, 0.f, 0.f, 0.f};
            #pragma unroll
            for (int kk = 0; kk < 8; ++kk) {
              bf16x8 bv = ok ? ldfrag_nt(bp + kk * 32 + ko) : bf16x8{};
              acc = MFMA16(afr[kk], bv, acc);
            }
            if (ok) {
              float bb = a.bout[c];
              #pragma unroll
              for (int reg = 0; reg < 4; ++reg) {
                int nrow = w4 * 16 + 4 * lg + reg;
                __builtin_nontemporal_store(
                    acc[reg] + bb, &a.out[((size_t)nrow * TDEC + t) * VOCAB + c]);
              }
            }
          }
        }
      }
    }
    return;
  }

  // ======================= attention helper WGs (64..127) =================
  if (wg >= 64) {
    if (!a.big) return;
    const int n = wg - 64;
    const int len = a.slen[n];
    for (int t = 0; t < TDEC - 1; ++t) {
      if (tid == 0) {
        unsigned need = 3u * (unsigned)t + 3u;  // L2P(t) done
        while (__hip_atomic_load(a.bar_rel, __ATOMIC_RELAXED,
                                 __HIP_MEMORY_SCOPE_AGENT) < need)
          __builtin_amdgcn_s_sleep(4);
      }
      __syncthreads();
      if (tid < 64) {  // stage h2(t)
        unsigned u = *(const unsigned*)((const unsigned short*)a.h2cbf +
                                        ((size_t)t * NB + n) * 256 + 2 * tid);
        h2s[2 * tid] = bf2f(u & 0xffffu);
        h2s[2 * tid + 1] = bf2f(u >> 16);
      }
      __syncthreads();
      int p = 250 + tid;
      float e = -1e30f;
      if (tid < 250 && p < len) {
        float s = 0.f;
        if (a.kv) {
          const uint4* kr = (const uint4*)(a.keybf + ((size_t)n * TENC + p) * KSZ);
          #pragma unroll
          for (int kk = 0; kk < 16; ++kk) {
            uint4 u = kr[kk];
            const float* hh = &h2s[kk * 8];
            s += bf2f(u.x & 0xffffu) * hh[0] + bf2f(u.x >> 16) * hh[1]
               + bf2f(u.y & 0xffffu) * hh[2] + bf2f(u.y >> 16) * hh[3]
               + bf2f(u.z & 0xffffu) * hh[4] + bf2f(u.z >> 16) * hh[5]
               + bf2f(u.w & 0xffffu) * hh[6] + bf2f(u.w >> 16) * hh[7];
          }
        } else {
          const float4* kr = (const float4*)(a.key + ((size_t)n * TENC + p) * KSZ);
          #pragma unroll 8
          for (int kk = 0; kk < 32; ++kk) {
            float4 u = kr[kk];
            const float* hh = &h2s[kk * 4];
            s += u.x * hh[0] + u.y * hh[1] + u.z * hh[2] + u.w * hh[3];
          }
        }
        e = s;
      }
      red[tid] = e;
      __syncthreads();
      for (int s2 = 256; s2 > 0; s2 >>= 1) {
        if (tid < s2) red[tid] = fmaxf(red[tid], red[tid + s2]);
        __syncthreads();
      }
      float mB = red[0];
      __syncthreads();
      float ex = (tid < 250 && p < len) ? __expf(e - mB) : 0.f;
      e_l[tid] = ex;
      red[tid] = ex;
      __syncthreads();
      for (int s2 = 256; s2 > 0; s2 >>= 1) {
        if (tid < s2) red[tid] += red[tid + s2];
        __syncthreads();
      }
      float SB = red[0];
      {  // PV over [250, len)
        int w = tid >> 6, ln = tid & 63;
        float a0 = 0.f, a1 = 0.f;
        if (a.kv) {
          const unsigned short* vb = (const unsigned short*)a.valbf;
          for (int p2 = 250 + w; p2 < len; p2 += 8) {
            unsigned u = *(const unsigned*)(vb + ((size_t)n * TENC + p2) * VSZ + 2 * ln);
            float ew = e_l[p2 - 250];
            a0 += ew * bf2f(u & 0xffffu);
            a1 += ew * bf2f(u >> 16);
          }
        } else {
          for (int p2 = 250 + w; p2 < len; p2 += 8) {
            float2 vv = *(const float2*)(a.value + ((size_t)n * TENC + p2) * VSZ + 2 * ln);
            float ew = e_l[p2 - 250];
            a0 += ew * vv.x;
            a1 += ew * vv.y;
          }
        }
        ctxp[w * 128 + 2 * ln] = a0;
        ctxp[w * 128 + 2 * ln + 1] = a1;
      }
      __syncthreads();
      if (tid < 64) {
        int vp = tid;
        float p0 = 0.f, p1 = 0.f;
        #pragma unroll
        for (int w2 = 0; w2 < 8; ++w2) {
          p0 += ctxp[w2 * 128 + 2 * vp];
          p1 += ctxp[w2 * 128 + 2 * vp + 1];
        }
        st_u32_sys(a.pbuf + n * 128 + 2 * vp, pack2bf(p0, p1));
      }
      if (tid == 0) {
        st_u32_sys(a.ms + n * 2, __float_as_uint(mB));
        st_u32_sys(a.ms + n * 2 + 1, __float_as_uint(SB));
      }
      asm volatile("s_waitcnt vmcnt(0)" ::: "memory");
      __syncthreads();
      if (tid == 0) st_u32_sys(&a.flags[n], (unsigned)(t + 1));
    }
    return;
  }

  // ======================= recurrence WGs (0..63) =========================
  const int lane = tid & 63, wid = tid >> 6;
  const int ln15 = lane & 15, lg = lane >> 4, ko = lg * 8;
  const int bg = wid & 3, kh = wid >> 2;
  const int d0 = wg * 16;
  const bool inv = (a.big == 0);

  float creg0 = 0.f, creg1 = 0.f;  // c1 (2 dims/thread, phase B tail)
  float creg2 = 0.f;               // c2 (1 dim/thread, L2P tail, tid<256)

  const __hip_bfloat16 *wb0, *wb1, *wb2, *wb3;
  {
    int g = ln15 & 3, s = ln15 >> 2;
    wb0 = a.W1bf + (size_t)(g * 1024 + d0 + 0 + s) * K1;
    wb1 = a.W1bf + (size_t)(g * 1024 + d0 + 4 + s) * K1;
    wb2 = a.W1bf + (size_t)(g * 1024 + d0 + 8 + s) * K1;
    wb3 = a.W1bf + (size_t)(g * 1024 + d0 + 12 + s) * K1;
  }
  const __hip_bfloat16* w2p =
      a.W2bf + (size_t)((ln15 & 3) * 128 + (wg & 31) * 4 + (ln15 >> 2)) * K2;
  const int nA = bg * 16 + ln15;  // A-operand batch row for this lane
  const int n = wg;               // A: one batch row per WG
  const int len = a.slen[n];

  // -------------------------------- prologue: biases, ctx0 = mean(V)
  if (tid < 64) bs1l[tid >> 2][tid & 3] = a.bsum1[(tid & 3) * 1024 + d0 + (tid >> 2)];
  {
    int v = tid & 127, ph = tid >> 7;  // ph 0..3
    float acc = 0.f;
    if (a.kv) {
      const unsigned short* vb = (const unsigned short*)a.valbf;
      for (int p = ph; p < len; p += 4)
        acc += bf2f(vb[((size_t)n * TENC + p) * VSZ + v]);
    } else {
      for (int p = ph; p < len; p += 4)
        acc += a.value[((size_t)n * TENC + p) * VSZ + v];
    }
    ctxp[ph * 128 + v] = acc;
  }
  __syncthreads();
  if (tid < 64) {
    int vp = tid;
    float invl = 1.f / (float)len;
    float c0 = (ctxp[0 * 128 + 2 * vp] + ctxp[1 * 128 + 2 * vp] +
                ctxp[2 * 128 + 2 * vp] + ctxp[3 * 128 + 2 * vp]) * invl;
    float c1 = (ctxp[0 * 128 + 2 * vp + 1] + ctxp[1 * 128 + 2 * vp + 1] +
                ctxp[2 * 128 + 2 * vp + 1] + ctxp[3 * 128 + 2 * vp + 1]) * invl;
    unsigned pk = pack2bf(c0, c1);
    st_u32_sys(a.ctxr + (size_t)n * 128 + 2 * vp, pk);  // ring slot 0
    st_u32_sys(&a.h2cbf[((size_t)0 * NB + n) * 256 + 128 + 2 * vp], pk);
  }
  int ep = 0;
  gbar(a.bar_cnt, a.bar_rel, ++ep, wg, inv);

  // -------------------------------- main loop
  for (int t = 0; t < TDEC; ++t) {
    const __hip_bfloat16 *h1c, *ctxc;
    __hip_bfloat16 *h1n, *ctxn;
    if (a.big) {
      h1c = a.h1r + (size_t)t * 65536;
      h1n = a.h1r + (size_t)(t + 1) * 65536;
      ctxc = a.ctxr + (size_t)t * 8192;
      ctxn = a.ctxr + (size_t)(t + 1) * 8192;
    } else {
      h1c = a.h1r + (size_t)(t & 1) * 65536;
      h1n = a.h1r + (size_t)((t + 1) & 1) * 65536;
      ctxc = a.ctxr;
      ctxn = a.ctxr;
    }

    // ---------- phase B: LSTM1 (64 WGs; WG owns 16 h1 dims)
    {
      const __hip_bfloat16* ax = a.xembbf + ((size_t)t * NB + nA) * EMBD;
      const __hip_bfloat16* ac = ctxc + nA * 128;
      const __hip_bfloat16* ah = h1c + nA * 1024;
      f32x4 q0 = {0, 0, 0, 0}, q1 = {0, 0, 0, 0}, q2 = {0, 0, 0, 0}, q3 = {0, 0, 0, 0};
      if (kh == 0) {
        #pragma unroll
        for (int s = 0; s < 16; ++s) {
          bf16x8 av = ldfrag(ax + s * 32 + ko);
          int o = s * 32 + ko;
          q0 = MFMA16(av, ldfrag(wb0 + o), q0);
          q1 = MFMA16(av, ldfrag(wb1 + o), q1);
          q2 = MFMA16(av, ldfrag(wb2 + o), q2);
          q3 = MFMA16(av, ldfrag(wb3 + o), q3);
        }
        #pragma unroll
        for (int s = 0; s < 4; ++s) {
          bf16x8 av = ldfrag(ac + s * 32 + ko);
          int o = 512 + s * 32 + ko;
          q0 = MFMA16(av, ldfrag(wb0 + o), q0);
          q1 = MFMA16(av, ldfrag(wb1 + o), q1);
          q2 = MFMA16(av, ldfrag(wb2 + o), q2);
          q3 = MFMA16(av, ldfrag(wb3 + o), q3);
        }
        #pragma unroll
        for (int s = 0; s < 6; ++s) {
          bf16x8 av = ldfrag(ah + s * 32 + ko);
          int o = 640 + s * 32 + ko;
          q0 = MFMA16(av, ldfrag(wb0 + o), q0);
          q1 = MFMA16(av, ldfrag(wb1 + o), q1);
          q2 = MFMA16(av, ldfrag(wb2 + o), q2);
          q3 = MFMA16(av, ldfrag(wb3 + o), q3);
        }
      } else {
        #pragma unroll
        for (int s = 0; s < 26; ++s) {
          bf16x8 av = ldfrag(ah + 192 + s * 32 + ko);
          int o = 832 + s * 32 + ko;
          q0 = MFMA16(av, ldfrag(wb0 + o), q0);
          q1 = MFMA16(av, ldfrag(wb1 + o), q1);
          q2 = MFMA16(av, ldfrag(wb2 + o), q2);
          q3 = MFMA16(av, ldfrag(wb3 + o), q3);
        }
      }
      if (kh == 1) {
        *(f32x4*)&part[(((bg * 4 + 0) * 64) + lane) * 4] = q0;
        *(f32x4*)&part[(((bg * 4 + 1) * 64) + lane) * 4] = q1;
        *(f32x4*)&part[(((bg * 4 + 2) * 64) + lane) * 4] = q2;
        *(f32x4*)&part[(((bg * 4 + 3) * 64) + lane) * 4] = q3;
      }
      __syncthreads();
      if (kh == 0) {
        q0 += *(f32x4*)&part[(((bg * 4 + 0) * 64) + lane) * 4];
        q1 += *(f32x4*)&part[(((bg * 4 + 1) * 64) + lane) * 4];
        q2 += *(f32x4*)&part[(((bg * 4 + 2) * 64) + lane) * 4];
        q3 += *(f32x4*)&part[(((bg * 4 + 3) * 64) + lane) * 4];
        #pragma unroll
        for (int r = 0; r < 4; ++r) {
          gl[((bg * 4 + 0) * 16 + (lg * 4 + r)) * 16 + ln15] = q0[r];
          gl[((bg * 4 + 1) * 16 + (lg * 4 + r)) * 16 + ln15] = q1[r];
          gl[((bg * 4 + 2) * 16 + (lg * 4 + r)) * 16 + ln15] = q2[r];
          gl[((bg * 4 + 3) * 16 + (lg * 4 + r)) * 16 + ln15] = q3[r];
        }
      }
      __syncthreads();
      {  // tail: thread owns (n, dim-pair)
        int nn = tid >> 3, dp = tid & 7;
        int bgg = nn >> 4, ii = nn & 15;
        int t4 = dp >> 1, off = (dp & 1) * 8;
        float* gp = &gl[((bgg * 4 + t4) * 16 + ii) * 16 + off];
        float4 gA = *(float4*)gp;
        float4 gB = *(float4*)(gp + 4);
        int dA = dp * 2, dB = dp * 2 + 1;
        float I = sigm(gA.x + bs1l[dA][0]);
        float F = sigm(gA.y + bs1l[dA][1]);
        float G = ftanh(gA.z + bs1l[dA][2]);
        float O = sigm(gA.w + bs1l[dA][3]);
        float cv = F * creg0 + I * G;
        creg0 = cv;
        float hA = O * ftanh(cv);
        I = sigm(gB.x + bs1l[dB][0]);
        F = sigm(gB.y + bs1l[dB][1]);
        G = ftanh(gB.z + bs1l[dB][2]);
        O = sigm(gB.w + bs1l[dB][3]);
        cv = F * creg1 + I * G;
        creg1 = cv;
        float hB = O * ftanh(cv);
        st_u32_sys(h1n + nn * 1024 + d0 + dA, pack2bf(hA, hB));
      }
    }
    gbar(a.bar_cnt, a.bar_rel, ++ep, wg, inv);

    // ---------- phase L2P: LSTM2 dim-parallel MFMA (WGs 0..31, 4 dims each)
    if (wg < 32) {
      const int e0 = wg * 4;
      const __hip_bfloat16* ah = h1n + nA * 1024;
      f32x4 q = {0.f, 0.f, 0.f, 0.f};
      if (kh == 0) {
        #pragma unroll
        for (int s = 0; s < 18; ++s)
          q = MFMA16(ldfrag(ah + s * 32 + ko), ldfrag(w2p + s * 32 + ko), q);
      } else {
        #pragma unroll
        for (int s = 0; s < 14; ++s)
          q = MFMA16(ldfrag(ah + 576 + s * 32 + ko), ldfrag(w2p + 576 + s * 32 + ko), q);
        if (t > 0) {
          const __hip_bfloat16* hp = a.h2cbf + ((size_t)(t - 1) * NB + nA) * 256;
          #pragma unroll
          for (int s = 0; s < 4; ++s)
            q = MFMA16(ldfrag(hp + s * 32 + ko), ldfrag(w2p + 1024 + s * 32 + ko), q);
        }
      }
      if (kh == 1) *(f32x4*)&partL[(bg * 64 + lane) * 4] = q;
      __syncthreads();
      if (kh == 0) {
        q += *(f32x4*)&partL[(bg * 64 + lane) * 4];
        #pragma unroll
        for (int r = 0; r < 4; ++r)
          glL[(bg * 16 + lg * 4 + r) * 16 + ln15] = q[r];
      }
      __syncthreads();
      if (tid < 256) {
        int n2 = tid >> 2, ds = tid & 3;
        float4 g4 = *(float4*)&glL[((n2 >> 4) * 16 + (n2 & 15)) * 16 + ds * 4];
        int d = e0 + ds;
        float I = sigm(g4.x + a.bsum2[d]);
        float F = sigm(g4.y + a.bsum2[128 + d]);
        float G = ftanh(g4.z + a.bsum2[256 + d]);
        float O = sigm(g4.w + a.bsum2[384 + d]);
        float cv = F * creg2 + I * G;
        creg2 = cv;
        float h = O * ftanh(cv);
        __hip_bfloat16 hb = __float2bfloat16(h);
        h2tmp[n2 * 4 + ds] = *(unsigned short*)&hb;
      }
      __syncthreads();
      if (tid < 128) {
        int n3 = tid >> 1, e = tid & 1;
        unsigned pk = (unsigned)h2tmp[n3 * 4 + 2 * e] |
                      ((unsigned)h2tmp[n3 * 4 + 2 * e + 1] << 16);
        st_u32_sys(&a.h2cbf[((size_t)t * NB + n3) * 256 + e0 + 2 * e], pk);
      }
    }
    gbar(a.bar_cnt, a.bar_rel, ++ep, wg, inv);

    // ---------- phase A: attention, main half [0,250) + helper merge
    if (t < TDEC - 1) {
      if (tid < 64) {  // stage h2(t) row n -> LDS f32
        unsigned u = *(const unsigned*)((const unsigned short*)a.h2cbf +
                                        ((size_t)t * NB + n) * 256 + 2 * tid);
        h2s[2 * tid] = bf2f(u & 0xffffu);
        h2s[2 * tid + 1] = bf2f(u >> 16);
      }
      __syncthreads();
      const int lim = a.big ? (len < 250 ? len : 250) : len;
      float e = -1e30f;
      if (tid < lim) {
        float s = 0.f;
        if (a.kv) {
          const uint4* kr = (const uint4*)(a.keybf + ((size_t)n * TENC + tid) * KSZ);
          #pragma unroll
          for (int kk = 0; kk < 16; ++kk) {
            uint4 u = kr[kk];
            const float* hh = &h2s[kk * 8];
            s += bf2f(u.x & 0xffffu) * hh[0] + bf2f(u.x >> 16) * hh[1]
               + bf2f(u.y & 0xffffu) * hh[2] + bf2f(u.y >> 16) * hh[3]
               + bf2f(u.z & 0xffffu) * hh[4] + bf2f(u.z >> 16) * hh[5]
               + bf2f(u.w & 0xffffu) * hh[6] + bf2f(u.w >> 16) * hh[7];
          }
        } else {
          const float4* kr = (const float4*)(a.key + ((size_t)n * TENC + tid) * KSZ);
          #pragma unroll 8
          for (int kk = 0; kk < 32; ++kk) {
            float4 u = kr[kk];
            const float* hh = &h2s[kk * 4];
            s += u.x * hh[0] + u.y * hh[1] + u.z * hh[2] + u.w * hh[3];
          }
        }
        e = s;
      }
      red[tid] = e;
      __syncthreads();
      for (int s2 = 256; s2 > 0; s2 >>= 1) {
        if (tid < s2) red[tid] = fmaxf(red[tid], red[tid + s2]);
        __syncthreads();
      }
      float mA = red[0];
      __syncthreads();
      float ex = (tid < lim) ? __expf(e - mA) : 0.f;
      e_l[tid] = ex;
      red[tid] = ex;
      __syncthreads();
      for (int s2 = 256; s2 > 0; s2 >>= 1) {
        if (tid < s2) red[tid] += red[tid + s2];
        __syncthreads();
      }
      float SA = red[0];
      {  // PV over [0, lim)
        int w = tid >> 6, ln = tid & 63;
        float a0 = 0.f, a1 = 0.f;
        if (a.kv) {
          const unsigned short* vb = (const unsigned short*)a.valbf;
          for (int p = w; p < lim; p += 8) {
            unsigned u = *(const unsigned*)(vb + ((size_t)n * TENC + p) * VSZ + 2 * ln);
            float ew = e_l[p];
            a0 += ew * bf2f(u & 0xffffu);
            a1 += ew * bf2f(u >> 16);
          }
        } else {
          for (int p = w; p < lim; p += 8) {
            float2 vv = *(const float2*)(a.value + ((size_t)n * TENC + p) * VSZ + 2 * ln);
            float ew = e_l[p];
            a0 += ew * vv.x;
            a1 += ew * vv.y;
          }
        }
        ctxp[w * 128 + 2 * ln] = a0;
        ctxp[w * 128 + 2 * ln + 1] = a1;
      }
      __syncthreads();
      if (a.big && tid == 0) {  // wait for helper's half
        while (__hip_atomic_load(&a.flags[n], __ATOMIC_RELAXED,
                                 __HIP_MEMORY_SCOPE_AGENT) < (unsigned)(t + 1))
          __builtin_amdgcn_s_sleep(2);
      }
      __syncthreads();
      if (tid < 64) {
        int vp = tid;
        float PA0 = 0.f, PA1 = 0.f;
        #pragma unroll
        for (int w2 = 0; w2 < 8; ++w2) {
          PA0 += ctxp[w2 * 128 + 2 * vp];
          PA1 += ctxp[w2 * 128 + 2 * vp + 1];
        }
        float c0, c1;
        if (a.big) {
          float mB = __uint_as_float(ld_u32_sys(a.ms + n * 2));
          float SB = __uint_as_float(ld_u32_sys(a.ms + n * 2 + 1));
          unsigned pbu = ld_u32_sys(a.pbuf + n * 128 + 2 * vp);
          float m2 = fmaxf(mA, mB);
          float fA = __expf(mA - m2), fB = __expf(mB - m2);
          float ivs = 1.f / (SA * fA + SB * fB);
          c0 = (PA0 * fA + bf2f(pbu & 0xffffu) * fB) * ivs;
          c1 = (PA1 * fA + bf2f(pbu >> 16) * fB) * ivs;
        } else {
          float ivs = 1.f / SA;
          c0 = PA0 * ivs;
          c1 = PA1 * ivs;
        }
        unsigned pk = pack2bf(c0, c1);
        st_u32_sys(ctxn + (size_t)n * 128 + 2 * vp, pk);
        st_u32_sys(&a.h2cbf[((size_t)(t + 1) * NB + n) * 256 + 128 + 2 * vp], pk);
      }
    }
    gbar(a.bar_cnt, a.bar_rel, ++ep, wg, inv);
  }
}

// ---------------------------------------------------------------------------
extern "C" void kernel_launch(void* const* d_in, const int* in_sizes, int n_in,
                              void* d_out, int out_size, void* d_ws, size_t ws_size,
                              hipStream_t stream) {
  (void)in_sizes; (void)n_in; (void)out_size;
  const float* key   = (const float*)d_in[0];
  const float* value = (const float*)d_in[1];
  const int*   slen  = (const int*)d_in[2];
  const int*   text  = (const int*)d_in[3];
  const float* emb   = (const float*)d_in[4];
  const float* Wih1  = (const float*)d_in[5];
  const float* Whh1  = (const float*)d_in[6];
  const float* bih1  = (const float*)d_in[7];
  const float* bhh1  = (const float*)d_in[8];
  const float* Wih2  = (const float*)d_in[9];
  const float* Whh2  = (const float*)d_in[10];
  const float* bih2  = (const float*)d_in[11];
  const float* bhh2  = (const float*)d_in[12];
  const float* Wout  = (const float*)d_in[13];
  const float* bout  = (const float*)d_in[14];
  float* out = (float*)d_out;
  char* ws = (char*)d_ws;

  int big = (ws_size >= BIG_END) ? 1 : 0;
  int kv  = (ws_size >= KV_END) ? 1 : 0;

  __hip_bfloat16* W1bf   = (__hip_bfloat16*)(ws + OFF_W1);
  __hip_bfloat16* W2bf   = (__hip_bfloat16*)(ws + OFF_W2);
  __hip_bfloat16* Woutbf = (__hip_bfloat16*)(ws + OFF_WOUT);
  __hip_bfloat16* xembbf = (__hip_bfloat16*)(ws + OFF_XEMB);
  __hip_bfloat16* h2cbf  = (__hip_bfloat16*)(ws + OFF_H2C);
  float* bsum1 = (float*)(ws + OFF_BS1);
  float* bsum2 = (float*)(ws + OFF_BS2);
  __hip_bfloat16* keybf = (__hip_bfloat16*)(ws + OFF_KEYBF);
  __hip_bfloat16* valbf = (__hip_bfloat16*)(ws + OFF_VALBF);

  hipMemsetAsync(ws, 0, 4096, stream);                 // barrier flags + ms + helper flags
  hipMemsetAsync(ws + OFF_H1R, 0, 262144, stream);     // h1 ring slots 0,1
  k_prep_w1<<<4096, 256, 0, stream>>>(Wih1, Whh1, bih1, bhh1, W1bf, bsum1);
  k_prep_w2<<<512, 256, 0, stream>>>(Wih2, Whh2, bih2, bhh2, W2bf, bsum2);
  k_prep_wout<<<625, 256, 0, stream>>>(Wout, Woutbf);
  k_gather<<<TDEC, 256, 0, stream>>>(text, emb, xembbf);
  if (kv) k_prep_kv<<<2048, 256, 0, stream>>>(key, value, keybf, valbf);

  LA la;
  la.key = key; la.value = value; la.slen = slen;
  la.keybf = keybf; la.valbf = valbf; la.kv = kv; la.big = big;
  la.W1bf = W1bf; la.W2bf = W2bf; la.Woutbf = Woutbf; la.xembbf = xembbf;
  la.bsum1 = bsum1; la.bsum2 = bsum2; la.bout = bout; la.out = out;
  la.h1r = (__hip_bfloat16*)(ws + OFF_H1R);
  la.ctxr = (__hip_bfloat16*)(ws + OFF_CTXR);
  la.h2cbf = h2cbf;
  la.pbuf = (__hip_bfloat16*)(ws + OFF_CTXR) + (size_t)200 * 8192;  // ctxr slot 200
  la.ms = (unsigned*)(ws + 2048);
  la.flags = (unsigned*)(ws + 2560);
  la.bar_cnt = (unsigned*)(ws + OFF_BAR);
  la.bar_rel = (unsigned*)(ws + OFF_BAR + 1024);

  void* args[] = {&la};
  hipLaunchCooperativeKernel((void*)k_loop, dim3(NWG), dim3(NTH), args, 0, stream);
}

// Round 12
// 9172.069 us; speedup vs baseline: 3.1738x; 1.3213x over previous
//
#include <hip/hip_runtime.h>
#include <hip/hip_bf16.h>
#include <math.h>

// ---------------------------------------------------------------------------
// Round 12: widen the latency-bound phases (B: 64->128 WGs @8 dims; L2P:
// 32->64 WGs @2 dims) to double miss-level parallelism (r7-r11 invariant:
// dur == FETCH / ~150GB/s == MSHR-limited on 64/32 CUs), and replace the
// master+release barrier with a direct-poll barrier (each WG polls the 8
// counters; helpers become participants so their h2c wait is the barrier).
// A-split (main [0,250) + helper [250,len)), NT Wout/out unchanged from r11.
// ---------------------------------------------------------------------------

#define NB    64
#define TENC  500
#define TDEC  200
#define EMBD  512
#define HID   1024
#define KSZ   128
#define VSZ   128
#define VOCAB 10000
#define K1    1664
#define K2    1152
#define NWG   256
#define NTH   512

typedef __bf16 bf16x8 __attribute__((ext_vector_type(8)));
typedef float f32x4 __attribute__((ext_vector_type(4)));
typedef unsigned long long u64;
#define MFMA16(a, b, c) __builtin_amdgcn_mfma_f32_16x16x32_bf16((a), (b), (c), 0, 0, 0)

// ws layout (bytes)
constexpr size_t OFF_BAR   = 0;          // cnt 8x64B @0; ms @2048; flags @2560
constexpr size_t OFF_BS1   = 4096;       // f32 [4096]
constexpr size_t OFF_BS2   = 20480;      // f32 [512]
constexpr size_t OFF_W2    = 22528;      // bf16 [512][1152] = 1179648
constexpr size_t OFF_H2C   = 1202176;    // bf16 [12800][256] = 6553600
constexpr size_t OFF_W1    = 7755776;    // bf16 [4096][1664] = 13631488
constexpr size_t OFF_WOUT  = 21387264;   // bf16 [10000][256] = 5120000
constexpr size_t OFF_XEMB  = 26507264;   // bf16 [200][64][512] = 13107200
constexpr size_t OFF_H1R   = 39614464;   // bf16 [201][64][1024] = 26345472
constexpr size_t OFF_CTXR  = 65959936;   // bf16 [201][64][128]; slot 200 = helper P
constexpr size_t BIG_END   = 69253120;
constexpr size_t OFF_KEYBF = 69253120;   // bf16 [64][500][128]
constexpr size_t OFF_VALBF = 77445120;   // bf16 [64][500][128]
constexpr size_t KV_END    = 85637120;

__device__ __forceinline__ float sigm(float x) { return 1.0f / (1.0f + __expf(-x)); }
__device__ __forceinline__ float ftanh(float x) {
  float ax = fabsf(x);
  float e = __expf(2.0f * ax);
  float tv = 1.0f - 2.0f / (e + 1.0f);
  return copysignf(tv, x);
}
__device__ __forceinline__ float bf2f(unsigned u) { return __uint_as_float(u << 16); }
__device__ __forceinline__ bf16x8 ldfrag(const __hip_bfloat16* p) {
  return *reinterpret_cast<const bf16x8*>(p);
}
__device__ __forceinline__ bf16x8 ldfrag_nt(const __hip_bfloat16* p) {
  union { u64 u[2]; bf16x8 v; } r;
  r.u[0] = __builtin_nontemporal_load((const u64*)p);
  r.u[1] = __builtin_nontemporal_load((const u64*)(p + 4));
  return r.v;
}
__device__ __forceinline__ void st_u32_sys(void* p, unsigned v) {
  __hip_atomic_store((unsigned*)p, v, __ATOMIC_RELAXED, __HIP_MEMORY_SCOPE_AGENT);
}
__device__ __forceinline__ unsigned ld_u32_sys(const void* p) {
  return __hip_atomic_load((const unsigned*)p, __ATOMIC_RELAXED, __HIP_MEMORY_SCOPE_AGENT);
}
__device__ __forceinline__ unsigned pack2bf(float a, float b) {
  __hip_bfloat16 ha = __float2bfloat16(a), hb = __float2bfloat16(b);
  unsigned short ua = *(unsigned short*)&ha, ub = *(unsigned short*)&hb;
  return (unsigned)ua | ((unsigned)ub << 16);
}
__device__ __forceinline__ unsigned short f2bfu(float x) {
  __hip_bfloat16 h = __float2bfloat16(x);
  return *(unsigned short*)&h;
}

// ------------------------------------------------------------- prep kernels
__global__ __launch_bounds__(256) void k_prep_w1(const float* __restrict__ Wih1,
                                                 const float* __restrict__ Whh1,
                                                 const float* __restrict__ bih1,
                                                 const float* __restrict__ bhh1,
                                                 __hip_bfloat16* __restrict__ W1bf,
                                                 float* __restrict__ bsum1) {
  int r = blockIdx.x;
  const float* wi = Wih1 + (size_t)r * 640;
  const float* wh = Whh1 + (size_t)r * 1024;
  for (int k = threadIdx.x; k < K1; k += 256)
    W1bf[(size_t)r * K1 + k] = __float2bfloat16(k < 640 ? wi[k] : wh[k - 640]);
  if (threadIdx.x == 0) bsum1[r] = bih1[r] + bhh1[r];
}

__global__ __launch_bounds__(256) void k_prep_w2(const float* __restrict__ Wih2,
                                                 const float* __restrict__ Whh2,
                                                 const float* __restrict__ bih2,
                                                 const float* __restrict__ bhh2,
                                                 __hip_bfloat16* __restrict__ W2bf,
                                                 float* __restrict__ bsum2) {
  int r = blockIdx.x;  // 512 rows
  for (int k = threadIdx.x; k < K2; k += 256)
    W2bf[(size_t)r * K2 + k] =
        __float2bfloat16(k < 1024 ? Wih2[(size_t)r * 1024 + k]
                                  : Whh2[(size_t)r * 128 + k - 1024]);
  if (threadIdx.x == 0) bsum2[r] = bih2[r] + bhh2[r];
}

__global__ __launch_bounds__(256) void k_prep_wout(const float* __restrict__ Wout,
                                                   __hip_bfloat16* __restrict__ Woutbf) {
  int r0 = blockIdx.x * 16;
  for (int idx = threadIdx.x; idx < 16 * 256; idx += 256) {
    int r = r0 + (idx >> 8), k = idx & 255;
    Woutbf[(size_t)r * 256 + k] = __float2bfloat16(Wout[(size_t)r * 256 + k]);
  }
}

__global__ __launch_bounds__(256) void k_gather(const int* __restrict__ text,
                                                const float* __restrict__ emb,
                                                __hip_bfloat16* __restrict__ xembbf) {
  int t = blockIdx.x;
  __shared__ int tok[NB];
  if (threadIdx.x < NB) tok[threadIdx.x] = text[threadIdx.x * TDEC + t];
  __syncthreads();
  for (int idx = threadIdx.x; idx < NB * EMBD; idx += 256) {
    int n = idx >> 9, k = idx & 511;
    xembbf[((size_t)t * NB + n) * EMBD + k] =
        __float2bfloat16(emb[(size_t)tok[n] * EMBD + k]);
  }
}

__global__ __launch_bounds__(256) void k_prep_kv(const float* __restrict__ key,
                                                 const float* __restrict__ value,
                                                 __hip_bfloat16* __restrict__ keybf,
                                                 __hip_bfloat16* __restrict__ valbf) {
  int gsz = gridDim.x * 256;
  for (size_t i = blockIdx.x * 256 + threadIdx.x; i < (size_t)NB * TENC * KSZ; i += gsz) {
    keybf[i] = __float2bfloat16(key[i]);
    valbf[i] = __float2bfloat16(value[i]);
  }
}

// -------- direct-poll grid barrier: 128 participants, 16 per counter group
__device__ __forceinline__ void gbar(unsigned* cnt, int ep, int wg, bool inv) {
  asm volatile("s_waitcnt vmcnt(0)" ::: "memory");
  __syncthreads();
  int tid = threadIdx.x;
  if (tid == 0) {
    if (inv)
      __hip_atomic_fetch_add(&cnt[(wg & 7) << 4], 1u, __ATOMIC_ACQ_REL,
                             __HIP_MEMORY_SCOPE_AGENT);
    else
      __hip_atomic_fetch_add(&cnt[(wg & 7) << 4], 1u, __ATOMIC_RELAXED,
                             __HIP_MEMORY_SCOPE_AGENT);
  }
  if (tid < 64) {
    unsigned need = (unsigned)ep * 16u;
    for (;;) {
      unsigned v = __hip_atomic_load(&cnt[(tid & 7) << 4], __ATOMIC_RELAXED,
                                     __HIP_MEMORY_SCOPE_AGENT);
      if (__all((int)(v >= need))) break;
      __builtin_amdgcn_s_sleep(1);
    }
    if (inv) {
      unsigned vv = __hip_atomic_load(&cnt[(tid & 7) << 4], __ATOMIC_ACQUIRE,
                                      __HIP_MEMORY_SCOPE_AGENT);
      (void)vv;
    }
  }
  __syncthreads();
}

// ------------------------------------------------------- persistent kernel
struct LA {
  const float* key;
  const float* value;
  const int* slen;
  const __hip_bfloat16* keybf;
  const __hip_bfloat16* valbf;
  int kv;
  int big;
  const __hip_bfloat16* W1bf;
  const __hip_bfloat16* W2bf;
  const __hip_bfloat16* Woutbf;
  const __hip_bfloat16* xembbf;
  const float* bsum1;
  const float* bsum2;
  const float* bout;
  float* out;
  __hip_bfloat16* h1r;    // ring [201][64][1024] (big) / [2][64][1024] (small)
  __hip_bfloat16* ctxr;   // ring [201][64][128]
  __hip_bfloat16* h2cbf;  // [200*64][256]
  __hip_bfloat16* pbuf;   // helper P partials [64][128] (ctxr slot 200)
  unsigned* ms;           // helper m,S [64][2]
  unsigned* flags;        // helper flags [64]
  unsigned* bar_cnt;
};

__global__ __launch_bounds__(NTH) void k_loop(LA a) {
  const int wg = blockIdx.x, tid = threadIdx.x;

  __shared__ float bs1l[8][4];
  __shared__ unsigned short stmp[512];
  __shared__ __align__(16) char smem[33792];
  float* part = (float*)smem;            // B:   [4][2][64][4] f32 (8KB)
  float* gl   = (float*)(smem + 8192);   // B:   [4][2][16][16] f32 (8KB)
  float* partL = (float*)smem;           // L2P: [4][64][4] f32 (4KB)
  float* glL   = (float*)(smem + 4096);  // L2P: [4][16][16] f32 (4KB)
  float* h2s  = (float*)smem;            // A: [128] f32
  float* e_l  = (float*)(smem + 2048);   // A: [512] f32
  float* red  = (float*)(smem + 4096);   // A: [512] f32
  float* ctxp = (float*)(smem + 6144);   // A: [8][128] f32

  // ======================= output-projection WGs (128..255) ===============
  if (wg >= 128) {
    int o0 = wg - 128;
    int lane = tid & 63, w4 = tid >> 6;
    int ln15 = lane & 15, lg = lane >> 4, ko = lg * 8;
    for (int t = 0; t < TDEC; ++t) {
      if (tid < 64) {  // wait until L2P(t) barrier complete (h2c(t) ready)
        unsigned need = (3u * (unsigned)t + 3u) * 16u;
        for (;;) {
          unsigned v = __hip_atomic_load(&a.bar_cnt[(tid & 7) << 4],
                                         __ATOMIC_RELAXED, __HIP_MEMORY_SCOPE_AGENT);
          if (__all((int)(v >= need))) break;
          __builtin_amdgcn_s_sleep(8);
        }
      }
      __syncthreads();
      if (w4 < 4) {
        const __hip_bfloat16* ap =
            a.h2cbf + ((size_t)t * NB + w4 * 16 + ln15) * 256;
        bf16x8 afr[8];
        #pragma unroll
        for (int kk = 0; kk < 8; ++kk) afr[kk] = ldfrag(ap + kk * 32 + ko);
        for (int sub = 0; sub < 2; ++sub) {
          int o = o0 + sub * 128;
          if (o >= 157) break;
          int c0 = o * 64;
          #pragma unroll
          for (int s = 0; s < 4; ++s) {
            int c = c0 + s * 16 + ln15;
            bool ok = c < VOCAB;
            const __hip_bfloat16* bp = a.Woutbf + (size_t)c * 256;
            f32x4 acc = {0.f, 0.f, 0.f, 0.f};
            #pragma unroll
            for (int kk = 0; kk < 8; ++kk) {
              bf16x8 bv = ok ? ldfrag_nt(bp + kk * 32 + ko) : bf16x8{};
              acc = MFMA16(afr[kk], bv, acc);
            }
            if (ok) {
              float bb = a.bout[c];
              #pragma unroll
              for (int reg = 0; reg < 4; ++reg) {
                int nrow = w4 * 16 + 4 * lg + reg;
                __builtin_nontemporal_store(
                    acc[reg] + bb, &a.out[((size_t)nrow * TDEC + t) * VOCAB + c]);
              }
            }
          }
        }
      }
    }
    return;
  }

  // =========== recurrence WGs (0..127): B on all; L2P on 0..63; ===========
  // =========== A main on 0..63 (row wg), helper on 64..127 (row wg-64) ====
  const int lane = tid & 63, wid = tid >> 6;
  const int ln15 = lane & 15, lg = lane >> 4, ko = lg * 8;
  const int bg = wid & 3, kh = wid >> 2;
  const int d0 = wg * 8;              // 8 h1 dims per B-WG
  const bool inv = (a.big == 0);
  const bool isMain = (wg < 64);
  const int n = isMain ? wg : (wg - 64);  // A row for this WG
  const int len = a.slen[n];

  float creg0 = 0.f;  // c1 (1 dim/thread, B tail)
  float creg2 = 0.f;  // c2 (1 dim/thread, L2P tail, tid<128, wg<64)

  const __hip_bfloat16 *wb0, *wb1;
  {
    int g = ln15 & 3, s = ln15 >> 2;
    wb0 = a.W1bf + (size_t)(g * 1024 + d0 + 0 + s) * K1;
    wb1 = a.W1bf + (size_t)(g * 1024 + d0 + 4 + s) * K1;
  }
  const __hip_bfloat16* w2p;
  {
    int g = ln15 & 3, s = ln15 >> 2;
    if (s > 1) s = 1;  // duplicate rows for unused half of the frag
    w2p = a.W2bf + (size_t)(g * 128 + (wg & 63) * 2 + s) * K2;
  }
  const int nA = bg * 16 + ln15;  // MFMA A-operand batch row for this lane

  // -------------------------------- prologue: biases; ctx0 (main WGs only)
  if (tid < 32) bs1l[tid >> 2][tid & 3] = a.bsum1[(tid & 3) * 1024 + d0 + (tid >> 2)];
  if (isMain) {
    int v = tid & 127, ph = tid >> 7;  // ph 0..3
    float acc = 0.f;
    if (a.kv) {
      const unsigned short* vb = (const unsigned short*)a.valbf;
      for (int p = ph; p < len; p += 4)
        acc += bf2f(vb[((size_t)n * TENC + p) * VSZ + v]);
    } else {
      for (int p = ph; p < len; p += 4)
        acc += a.value[((size_t)n * TENC + p) * VSZ + v];
    }
    ctxp[ph * 128 + v] = acc;
    __syncthreads();
    if (tid < 64) {
      int vp = tid;
      float invl = 1.f / (float)len;
      float c0 = (ctxp[0 * 128 + 2 * vp] + ctxp[1 * 128 + 2 * vp] +
                  ctxp[2 * 128 + 2 * vp] + ctxp[3 * 128 + 2 * vp]) * invl;
      float c1 = (ctxp[0 * 128 + 2 * vp + 1] + ctxp[1 * 128 + 2 * vp + 1] +
                  ctxp[2 * 128 + 2 * vp + 1] + ctxp[3 * 128 + 2 * vp + 1]) * invl;
      unsigned pk = pack2bf(c0, c1);
      st_u32_sys(a.ctxr + (size_t)n * 128 + 2 * vp, pk);  // ring slot 0
      st_u32_sys(&a.h2cbf[((size_t)0 * NB + n) * 256 + 128 + 2 * vp], pk);
    }
  }
  int ep = 0;
  gbar(a.bar_cnt, ++ep, wg, inv);

  // -------------------------------- main loop
  for (int t = 0; t < TDEC; ++t) {
    const __hip_bfloat16 *h1c, *ctxc;
    __hip_bfloat16 *h1n, *ctxn;
    if (a.big) {
      h1c = a.h1r + (size_t)t * 65536;
      h1n = a.h1r + (size_t)(t + 1) * 65536;
      ctxc = a.ctxr + (size_t)t * 8192;
      ctxn = a.ctxr + (size_t)(t + 1) * 8192;
    } else {
      h1c = a.h1r + (size_t)(t & 1) * 65536;
      h1n = a.h1r + (size_t)((t + 1) & 1) * 65536;
      ctxc = a.ctxr;
      ctxn = a.ctxr;
    }

    // ---------- phase B: LSTM1 (128 WGs; WG owns 8 h1 dims)
    {
      const __hip_bfloat16* ax = a.xembbf + ((size_t)t * NB + nA) * EMBD;
      const __hip_bfloat16* ac = ctxc + nA * 128;
      const __hip_bfloat16* ah = h1c + nA * 1024;
      f32x4 q0 = {0, 0, 0, 0}, q1 = {0, 0, 0, 0};
      if (kh == 0) {
        #pragma unroll
        for (int s = 0; s < 16; ++s) {
          bf16x8 av = ldfrag(ax + s * 32 + ko);
          int o = s * 32 + ko;
          q0 = MFMA16(av, ldfrag(wb0 + o), q0);
          q1 = MFMA16(av, ldfrag(wb1 + o), q1);
        }
        #pragma unroll
        for (int s = 0; s < 4; ++s) {
          bf16x8 av = ldfrag(ac + s * 32 + ko);
          int o = 512 + s * 32 + ko;
          q0 = MFMA16(av, ldfrag(wb0 + o), q0);
          q1 = MFMA16(av, ldfrag(wb1 + o), q1);
        }
        #pragma unroll
        for (int s = 0; s < 6; ++s) {
          bf16x8 av = ldfrag(ah + s * 32 + ko);
          int o = 640 + s * 32 + ko;
          q0 = MFMA16(av, ldfrag(wb0 + o), q0);
          q1 = MFMA16(av, ldfrag(wb1 + o), q1);
        }
      } else {
        #pragma unroll
        for (int s = 0; s < 26; ++s) {
          bf16x8 av = ldfrag(ah + 192 + s * 32 + ko);
          int o = 832 + s * 32 + ko;
          q0 = MFMA16(av, ldfrag(wb0 + o), q0);
          q1 = MFMA16(av, ldfrag(wb1 + o), q1);
        }
      }
      if (kh == 1) {
        *(f32x4*)&part[(((bg * 2 + 0) * 64) + lane) * 4] = q0;
        *(f32x4*)&part[(((bg * 2 + 1) * 64) + lane) * 4] = q1;
      }
      __syncthreads();
      if (kh == 0) {
        q0 += *(f32x4*)&part[(((bg * 2 + 0) * 64) + lane) * 4];
        q1 += *(f32x4*)&part[(((bg * 2 + 1) * 64) + lane) * 4];
        #pragma unroll
        for (int r = 0; r < 4; ++r) {
          gl[((bg * 2 + 0) * 16 + (lg * 4 + r)) * 16 + ln15] = q0[r];
          gl[((bg * 2 + 1) * 16 + (lg * 4 + r)) * 16 + ln15] = q1[r];
        }
      }
      __syncthreads();
      {  // tail: thread owns (n, dim) — 512 threads, 1 dim each
        int nn = tid >> 3, dp = tid & 7;
        int bgg = nn >> 4, ii = nn & 15;
        int f = dp >> 2, s = dp & 3;
        float4 gA = *(float4*)&gl[(((bgg * 2 + f) * 16) + ii) * 16 + s * 4];
        float I = sigm(gA.x + bs1l[dp][0]);
        float F = sigm(gA.y + bs1l[dp][1]);
        float G = ftanh(gA.z + bs1l[dp][2]);
        float O = sigm(gA.w + bs1l[dp][3]);
        float cv = F * creg0 + I * G;
        creg0 = cv;
        stmp[nn * 8 + dp] = f2bfu(O * ftanh(cv));
      }
      __syncthreads();
      if (tid < 256) {
        int n3 = tid >> 2, e = tid & 3;
        unsigned pk = (unsigned)stmp[n3 * 8 + e * 2] |
                      ((unsigned)stmp[n3 * 8 + e * 2 + 1] << 16);
        st_u32_sys(h1n + n3 * 1024 + d0 + e * 2, pk);
      }
    }
    gbar(a.bar_cnt, ++ep, wg, inv);

    // ---------- phase L2P: LSTM2 dim-parallel (WGs 0..63, 2 dims each)
    if (isMain) {
      const int e0 = wg * 2;
      const __hip_bfloat16* ah = h1n + nA * 1024;
      f32x4 q = {0.f, 0.f, 0.f, 0.f};
      if (kh == 0) {
        #pragma unroll
        for (int s = 0; s < 18; ++s)
          q = MFMA16(ldfrag(ah + s * 32 + ko), ldfrag(w2p + s * 32 + ko), q);
      } else {
        #pragma unroll
        for (int s = 0; s < 14; ++s)
          q = MFMA16(ldfrag(ah + 576 + s * 32 + ko), ldfrag(w2p + 576 + s * 32 + ko), q);
        if (t > 0) {
          const __hip_bfloat16* hp = a.h2cbf + ((size_t)(t - 1) * NB + nA) * 256;
          #pragma unroll
          for (int s = 0; s < 4; ++s)
            q = MFMA16(ldfrag(hp + s * 32 + ko), ldfrag(w2p + 1024 + s * 32 + ko), q);
        }
      }
      if (kh == 1) *(f32x4*)&partL[(bg * 64 + lane) * 4] = q;
      __syncthreads();
      if (kh == 0) {
        q += *(f32x4*)&partL[(bg * 64 + lane) * 4];
        #pragma unroll
        for (int r = 0; r < 4; ++r)
          glL[(bg * 16 + lg * 4 + r) * 16 + ln15] = q[r];
      }
      __syncthreads();
      if (tid < 128) {
        int n2 = tid >> 1, ds = tid & 1;
        float4 g4 = *(float4*)&glL[((n2 >> 4) * 16 + (n2 & 15)) * 16 + ds * 4];
        int d = e0 + ds;
        float I = sigm(g4.x + a.bsum2[d]);
        float F = sigm(g4.y + a.bsum2[128 + d]);
        float G = ftanh(g4.z + a.bsum2[256 + d]);
        float O = sigm(g4.w + a.bsum2[384 + d]);
        float cv = F * creg2 + I * G;
        creg2 = cv;
        stmp[n2 * 2 + ds] = f2bfu(O * ftanh(cv));
      }
      __syncthreads();
      if (tid < 64) {
        unsigned pk = (unsigned)stmp[tid * 2] | ((unsigned)stmp[tid * 2 + 1] << 16);
        st_u32_sys(&a.h2cbf[((size_t)t * NB + tid) * 256 + e0], pk);
      }
    }
    gbar(a.bar_cnt, ++ep, wg, inv);

    // ---------- phase A: attention (main rows [0,250); helper [250,len))
    if (t < TDEC - 1 && (isMain || a.big)) {
      if (tid < 64) {  // stage h2(t) row n -> LDS f32
        unsigned u = *(const unsigned*)((const unsigned short*)a.h2cbf +
                                        ((size_t)t * NB + n) * 256 + 2 * tid);
        h2s[2 * tid] = bf2f(u & 0xffffu);
        h2s[2 * tid + 1] = bf2f(u >> 16);
      }
      __syncthreads();
      const int base = isMain ? 0 : 250;
      const int lim = isMain ? (a.big ? (len < 250 ? len : 250) : len)
                             : len;        // helper covers [250, len)
      int p = base + tid;
      float e = -1e30f;
      if (tid < 250 + (isMain ? 6 : 0) && p < lim) {  // main covers up to 256 ids
        float s = 0.f;
        if (a.kv) {
          const uint4* kr = (const uint4*)(a.keybf + ((size_t)n * TENC + p) * KSZ);
          #pragma unroll
          for (int kk = 0; kk < 16; ++kk) {
            uint4 u = kr[kk];
            const float* hh = &h2s[kk * 8];
            s += bf2f(u.x & 0xffffu) * hh[0] + bf2f(u.x >> 16) * hh[1]
               + bf2f(u.y & 0xffffu) * hh[2] + bf2f(u.y >> 16) * hh[3]
               + bf2f(u.z & 0xffffu) * hh[4] + bf2f(u.z >> 16) * hh[5]
               + bf2f(u.w & 0xffffu) * hh[6] + bf2f(u.w >> 16) * hh[7];
          }
        } else {
          const float4* kr = (const float4*)(a.key + ((size_t)n * TENC + p) * KSZ);
          #pragma unroll 8
          for (int kk = 0; kk < 32; ++kk) {
            float4 u = kr[kk];
            const float* hh = &h2s[kk * 4];
            s += u.x * hh[0] + u.y * hh[1] + u.z * hh[2] + u.w * hh[3];
          }
        }
        e = s;
      }
      red[tid] = e;
      __syncthreads();
      for (int s2 = 256; s2 > 0; s2 >>= 1) {
        if (tid < s2) red[tid] = fmaxf(red[tid], red[tid + s2]);
        __syncthreads();
      }
      float mA = red[0];
      __syncthreads();
      bool act = (tid < 250 + (isMain ? 6 : 0)) && (base + tid < lim);
      float ex = act ? __expf(e - mA) : 0.f;
      e_l[tid] = ex;
      red[tid] = ex;
      __syncthreads();
      for (int s2 = 256; s2 > 0; s2 >>= 1) {
        if (tid < s2) red[tid] += red[tid + s2];
        __syncthreads();
      }
      float SA = red[0];
      {  // PV over [base, lim)
        int w = tid >> 6, ln = tid & 63;
        float a0 = 0.f, a1 = 0.f;
        if (a.kv) {
          const unsigned short* vb = (const unsigned short*)a.valbf;
          for (int p2 = base + w; p2 < lim; p2 += 8) {
            unsigned u = *(const unsigned*)(vb + ((size_t)n * TENC + p2) * VSZ + 2 * ln);
            float ew = e_l[p2 - base];
            a0 += ew * bf2f(u & 0xffffu);
            a1 += ew * bf2f(u >> 16);
          }
        } else {
          for (int p2 = base + w; p2 < lim; p2 += 8) {
            float2 vv = *(const float2*)(a.value + ((size_t)n * TENC + p2) * VSZ + 2 * ln);
            float ew = e_l[p2 - base];
            a0 += ew * vv.x;
            a1 += ew * vv.y;
          }
        }
        ctxp[w * 128 + 2 * ln] = a0;
        ctxp[w * 128 + 2 * ln + 1] = a1;
      }
      __syncthreads();
      if (!isMain) {  // helper: publish partials + flag
        if (tid < 64) {
          int vp = tid;
          float p0 = 0.f, p1 = 0.f;
          #pragma unroll
          for (int w2 = 0; w2 < 8; ++w2) {
            p0 += ctxp[w2 * 128 + 2 * vp];
            p1 += ctxp[w2 * 128 + 2 * vp + 1];
          }
          st_u32_sys(a.pbuf + n * 128 + 2 * vp, pack2bf(p0, p1));
        }
        if (tid == 0) {
          st_u32_sys(a.ms + n * 2, __float_as_uint(mA));
          st_u32_sys(a.ms + n * 2 + 1, __float_as_uint(SA));
        }
        asm volatile("s_waitcnt vmcnt(0)" ::: "memory");
        __syncthreads();
        if (tid == 0) st_u32_sys(&a.flags[n], (unsigned)(t + 1));
      } else {  // main: merge with helper half
        if (a.big && tid == 0) {
          while (__hip_atomic_load(&a.flags[n], __ATOMIC_RELAXED,
                                   __HIP_MEMORY_SCOPE_AGENT) < (unsigned)(t + 1))
            __builtin_amdgcn_s_sleep(2);
        }
        __syncthreads();
        if (tid < 64) {
          int vp = tid;
          float PA0 = 0.f, PA1 = 0.f;
          #pragma unroll
          for (int w2 = 0; w2 < 8; ++w2) {
            PA0 += ctxp[w2 * 128 + 2 * vp];
            PA1 += ctxp[w2 * 128 + 2 * vp + 1];
          }
          float c0, c1;
          if (a.big) {
            float mB = __uint_as_float(ld_u32_sys(a.ms + n * 2));
            float SB = __uint_as_float(ld_u32_sys(a.ms + n * 2 + 1));
            unsigned pbu = ld_u32_sys(a.pbuf + n * 128 + 2 * vp);
            float m2 = fmaxf(mA, mB);
            float fA = __expf(mA - m2), fB = __expf(mB - m2);
            float ivs = 1.f / (SA * fA + SB * fB);
            c0 = (PA0 * fA + bf2f(pbu & 0xffffu) * fB) * ivs;
            c1 = (PA1 * fA + bf2f(pbu >> 16) * fB) * ivs;
          } else {
            float ivs = 1.f / SA;
            c0 = PA0 * ivs;
            c1 = PA1 * ivs;
          }
          unsigned pk = pack2bf(c0, c1);
          st_u32_sys(ctxn + (size_t)n * 128 + 2 * vp, pk);
          st_u32_sys(&a.h2cbf[((size_t)(t + 1) * NB + n) * 256 + 128 + 2 * vp], pk);
        }
      }
    }
    gbar(a.bar_cnt, ++ep, wg, inv);
  }
}

// ---------------------------------------------------------------------------
extern "C" void kernel_launch(void* const* d_in, const int* in_sizes, int n_in,
                              void* d_out, int out_size, void* d_ws, size_t ws_size,
                              hipStream_t stream) {
  (void)in_sizes; (void)n_in; (void)out_size;
  const float* key   = (const float*)d_in[0];
  const float* value = (const float*)d_in[1];
  const int*   slen  = (const int*)d_in[2];
  const int*   text  = (const int*)d_in[3];
  const float* emb   = (const float*)d_in[4];
  const float* Wih1  = (const float*)d_in[5];
  const float* Whh1  = (const float*)d_in[6];
  const float* bih1  = (const float*)d_in[7];
  const float* bhh1  = (const float*)d_in[8];
  const float* Wih2  = (const float*)d_in[9];
  const float* Whh2  = (const float*)d_in[10];
  const float* bih2  = (const float*)d_in[11];
  const float* bhh2  = (const float*)d_in[12];
  const float* Wout  = (const float*)d_in[13];
  const float* bout  = (const float*)d_in[14];
  float* out = (float*)d_out;
  char* ws = (char*)d_ws;

  int big = (ws_size >= BIG_END) ? 1 : 0;
  int kv  = (ws_size >= KV_END) ? 1 : 0;

  __hip_bfloat16* W1bf   = (__hip_bfloat16*)(ws + OFF_W1);
  __hip_bfloat16* W2bf   = (__hip_bfloat16*)(ws + OFF_W2);
  __hip_bfloat16* Woutbf = (__hip_bfloat16*)(ws + OFF_WOUT);
  __hip_bfloat16* xembbf = (__hip_bfloat16*)(ws + OFF_XEMB);
  __hip_bfloat16* h2cbf  = (__hip_bfloat16*)(ws + OFF_H2C);
  float* bsum1 = (float*)(ws + OFF_BS1);
  float* bsum2 = (float*)(ws + OFF_BS2);
  __hip_bfloat16* keybf = (__hip_bfloat16*)(ws + OFF_KEYBF);
  __hip_bfloat16* valbf = (__hip_bfloat16*)(ws + OFF_VALBF);

  hipMemsetAsync(ws, 0, 4096, stream);                 // counters + ms + flags
  hipMemsetAsync(ws + OFF_H1R, 0, 262144, stream);     // h1 ring slots 0,1
  k_prep_w1<<<4096, 256, 0, stream>>>(Wih1, Whh1, bih1, bhh1, W1bf, bsum1);
  k_prep_w2<<<512, 256, 0, stream>>>(Wih2, Whh2, bih2, bhh2, W2bf, bsum2);
  k_prep_wout<<<625, 256, 0, stream>>>(Wout, Woutbf);
  k_gather<<<TDEC, 256, 0, stream>>>(text, emb, xembbf);
  if (kv) k_prep_kv<<<2048, 256, 0, stream>>>(key, value, keybf, valbf);

  LA la;
  la.key = key; la.value = value; la.slen = slen;
  la.keybf = keybf; la.valbf = valbf; la.kv = kv; la.big = big;
  la.W1bf = W1bf; la.W2bf = W2bf; la.Woutbf = Woutbf; la.xembbf = xembbf;
  la.bsum1 = bsum1; la.bsum2 = bsum2; la.bout = bout; la.out = out;
  la.h1r = (__hip_bfloat16*)(ws + OFF_H1R);
  la.ctxr = (__hip_bfloat16*)(ws + OFF_CTXR);
  la.h2cbf = h2cbf;
  la.pbuf = (__hip_bfloat16*)(ws + OFF_CTXR) + (size_t)200 * 8192;  // ctxr slot 200
  la.ms = (unsigned*)(ws + 2048);
  la.flags = (unsigned*)(ws + 2560);
  la.bar_cnt = (unsigned*)(ws + OFF_BAR);

  void* args[] = {&la};
  hipLaunchCooperativeKernel((void*)k_loop, dim3(NWG), dim3(NTH), args, 0, stream);
}